// Round 10
// baseline (767.528 us; speedup 1.0000x reference)
//
#include <hip/hip_runtime.h>
#include <cstddef>
#include <cstdint>

#define IDIV(a, b) (((a) + (b) - 1) / (b))

typedef __attribute__((ext_vector_type(8))) short short8;
typedef __attribute__((ext_vector_type(8))) unsigned short ushort8v;
typedef __attribute__((ext_vector_type(4))) float f32x4;

__device__ inline ushort f2bf_rne(float x) {
  uint32_t u = __builtin_bit_cast(uint32_t, x);
  u += 0x7fff + ((u >> 16) & 1);
  return (ushort)(u >> 16);
}
__device__ inline float bf2f(ushort h) {
  uint32_t u = (uint32_t)h << 16;
  return __builtin_bit_cast(float, u);
}

// BN coefficients from raw sums
__device__ inline void bn_coeff(const float* __restrict__ sums, const float* __restrict__ g,
                                const float* __restrict__ bb, float invN, int H, int c,
                                float& sc, float& sh) {
  const float mean = sums[c] * invN;
  float var = sums[H + c] * invN - mean * mean;
  var = var < 0.f ? 0.f : var;
  sc = g[c] * rsqrtf(var + 1e-5f);
  sh = bb[c] - mean * sc;
}

// ---------------------------------------------------------------- utilities

__global__ void k_zero_i32(int* __restrict__ p, int n) {
  int i = blockIdx.x * blockDim.x + threadIdx.x;
  if (i < n) p[i] = 0;
}

__global__ void k_zero_f32(float* __restrict__ p, int n) {
  int i = blockIdx.x * blockDim.x + threadIdx.x;
  if (i < n) p[i] = 0.f;
}

// ---------------------------------------------------------------- CSR build

__global__ void k_count(const int* __restrict__ dst, int E, int* __restrict__ cnt) {
  int i = blockIdx.x * blockDim.x + threadIdx.x;
  if (i < E) atomicAdd(&cnt[dst[i]], 1);
}

__global__ void k_scan_partial(const int* __restrict__ cnt, int n, int* __restrict__ part) {
  __shared__ int sm[256];
  const int t = threadIdx.x;
  const int i = blockIdx.x * 256 + t;
  sm[t] = (i < n) ? cnt[i] : 0;
  __syncthreads();
  for (int off = 128; off > 0; off >>= 1) {
    if (t < off) sm[t] += sm[t + off];
    __syncthreads();
  }
  if (t == 0) part[blockIdx.x] = sm[0];
}

__global__ void k_scan_offsets(int* __restrict__ part, int nb) {
  __shared__ int sm[256];
  const int t = threadIdx.x;
  if (t < nb) sm[t] = part[t];
  __syncthreads();
  if (t == 0) {
    int run = 0;
    for (int i = 0; i < nb; ++i) { int v = sm[i]; sm[i] = run; run += v; }
  }
  __syncthreads();
  if (t < nb) part[t] = sm[t];
}

__global__ void k_scan_final(const int* __restrict__ cnt, int n, const int* __restrict__ part,
                             int* __restrict__ row_ptr) {
  __shared__ int sm[256];
  const int t = threadIdx.x;
  const int i = blockIdx.x * 256 + t;
  const int v = (i < n) ? cnt[i] : 0;
  sm[t] = v;
  __syncthreads();
  for (int off = 1; off < 256; off <<= 1) {
    int x = (t >= off) ? sm[t - off] : 0;
    __syncthreads();
    sm[t] += x;
    __syncthreads();
  }
  if (i < n) row_ptr[i] = part[blockIdx.x] + sm[t] - v;  // exclusive scan
}

__global__ void k_cursor_dis(const int* __restrict__ row_ptr, const int* __restrict__ cnt,
                             int* __restrict__ cursor, float* __restrict__ dis,
                             int* __restrict__ row_ptr_end, int n, int E) {
  int i = blockIdx.x * blockDim.x + threadIdx.x;
  if (i == 0) *row_ptr_end = E;
  if (i < n) {
    cursor[i] = row_ptr[i];
    dis[i] = rsqrtf((float)cnt[i] + 1.0f);
  }
}

__global__ void k_scatter(const int* __restrict__ src, const int* __restrict__ dst, int E,
                          int* __restrict__ cursor, int* __restrict__ col) {
  int i = blockIdx.x * blockDim.x + threadIdx.x;
  if (i < E) {
    int d = dst[i];
    int pos = atomicAdd(&cursor[d], 1);
    col[pos] = src[i];
  }
}

// ---------------------------------------------------------------- weight prep
// W[K][O] fp32 -> Wt_hi[O][K], Wt_lo[O][K] bf16 (transposed + hi/lo split)

struct WSpec { const float* W; ushort* hi; ushort* lo; int K; int O; };
struct WPack { WSpec s[9]; };

__global__ void k_wprep(WPack p) {
  const WSpec w = p.s[blockIdx.y];
  const int total = w.K * w.O;
  for (int i = blockIdx.x * 256 + threadIdx.x; i < total; i += gridDim.x * 256) {
    const int o = i / w.K;
    const int k = i - o * w.K;
    const float v = w.W[(size_t)k * w.O + o];
    const ushort h = f2bf_rne(v);
    w.hi[i] = h;
    w.lo[i] = f2bf_rne(v - bf2f(h));
  }
}

// ---------------------------------------------------------------- 4-wave MFMA GEMM (BM=128)
// C[N,O] = op(A)[N,K] @ W[K,O] (+bias). W pre-split transposed bf16 hi+lo.
// PRO: 0 = A bf16 passthrough; 1 = A fp32, cast to bf16; 2 = A bf16,
// BN+lrelu (coeff table in LDS) + on-the-fly hi/lo split (3 MFMAs).
// Depth-1 register double-buffer. STATS: fused col sum/sumsq.

template <int K, int O, int PRO, bool STATS, bool OUTBF, bool BIAS>
__launch_bounds__(256, 2)
__global__ void k_gemm4(const void* __restrict__ Av, const ushort* __restrict__ Whi,
                        const ushort* __restrict__ Wlo, const float* __restrict__ bias,
                        const float* __restrict__ psums, const float* __restrict__ pg,
                        const float* __restrict__ pbb, float invN,
                        void* __restrict__ Cout, float* __restrict__ sums, int N) {
  constexpr int BN = (O >= 128) ? 128 : O;
  constexpr int KS = K / 32;
  constexpr int WC = (BN == 128) ? 2 : 1;
  constexpr int WR = 4 / WC;
  constexpr int MF = (128 / WR) / 16;
  constexpr int NF = 4;

  const ushort* Ab = (const ushort*)Av;
  const float* Af = (const float*)Av;

  __shared__ float lcf[(PRO == 2) ? 2 * K : 2];

  const int bm = blockIdx.x * 128;
  const int bo = blockIdx.y * BN;
  const int t = threadIdx.x;
  const int w = t >> 6, l = t & 63;
  const int wr = w / WC, wc = w - wr * WC;
  const int r0 = wr * (MF * 16);
  const int c0 = wc * 64;
  const int lr = l & 15;
  const int lk = (l >> 4) * 8;

  if constexpr (PRO == 2) {
    for (int c = t; c < K; c += 256) {
      float sc, sh;
      bn_coeff(psums, pg, pbb, invN, K, c, sc, sh);
      lcf[c] = sc;
      lcf[K + c] = sh;
    }
    __syncthreads();
  }

  f32x4 acc[MF][NF];
  const f32x4 zero4 = {0.f, 0.f, 0.f, 0.f};
#pragma unroll
  for (int mf = 0; mf < MF; ++mf)
#pragma unroll
    for (int nf = 0; nf < NF; ++nf) acc[mf][nf] = zero4;

  int arow[MF];
#pragma unroll
  for (int mf = 0; mf < MF; ++mf) {
    const int r = bm + r0 + mf * 16 + lr;
    arow[mf] = r < N ? r : N - 1;
  }

  short8 ah[2][MF], al[2][MF];
  float4 rawf[2][MF][2];
  short8 bh[2][NF], bl[2][NF];

  auto ldB = [&](int ks, int b) {
#pragma unroll
    for (int nf = 0; nf < NF; ++nf) {
      const size_t boff = (size_t)(bo + c0 + nf * 16 + lr) * K + ks * 32 + lk;
      bh[b][nf] = *reinterpret_cast<const short8*>(&Whi[boff]);
      bl[b][nf] = *reinterpret_cast<const short8*>(&Wlo[boff]);
    }
  };
  auto ldA = [&](int ks, int b) {
#pragma unroll
    for (int mf = 0; mf < MF; ++mf) {
      const size_t base = (size_t)arow[mf] * K + ks * 32 + lk;
      if constexpr (PRO == 1) {
        rawf[b][mf][0] = *reinterpret_cast<const float4*>(&Af[base]);
        rawf[b][mf][1] = *reinterpret_cast<const float4*>(&Af[base + 4]);
      } else {
        ah[b][mf] = *reinterpret_cast<const short8*>(&Ab[base]);
      }
    }
  };
  auto cvtA = [&](int ks, int b) {
    if constexpr (PRO == 1) {
#pragma unroll
      for (int mf = 0; mf < MF; ++mf) {
        const float f[8] = {rawf[b][mf][0].x, rawf[b][mf][0].y, rawf[b][mf][0].z,
                            rawf[b][mf][0].w, rawf[b][mf][1].x, rawf[b][mf][1].y,
                            rawf[b][mf][1].z, rawf[b][mf][1].w};
        short8 hi;
#pragma unroll
        for (int j = 0; j < 8; ++j) hi[j] = (short)f2bf_rne(f[j]);
        ah[b][mf] = hi;
      }
    } else if constexpr (PRO == 2) {
      const int k0 = ks * 32 + lk;
      const float4 c0v = *reinterpret_cast<const float4*>(&lcf[k0]);
      const float4 c1v = *reinterpret_cast<const float4*>(&lcf[k0 + 4]);
      const float4 h0v = *reinterpret_cast<const float4*>(&lcf[K + k0]);
      const float4 h1v = *reinterpret_cast<const float4*>(&lcf[K + k0 + 4]);
      const float sc[8] = {c0v.x, c0v.y, c0v.z, c0v.w, c1v.x, c1v.y, c1v.z, c1v.w};
      const float sh[8] = {h0v.x, h0v.y, h0v.z, h0v.w, h1v.x, h1v.y, h1v.z, h1v.w};
#pragma unroll
      for (int mf = 0; mf < MF; ++mf) {
        float f[8];
#pragma unroll
        for (int j = 0; j < 8; ++j) {
          float x = bf2f((ushort)ah[b][mf][j]) * sc[j] + sh[j];
          f[j] = x > 0.f ? x : 0.01f * x;
        }
        short8 hi, lo;
#pragma unroll
        for (int j = 0; j < 8; ++j) {
          const ushort h = f2bf_rne(f[j]);
          hi[j] = (short)h;
          lo[j] = (short)f2bf_rne(f[j] - bf2f(h));
        }
        ah[b][mf] = hi;
        al[b][mf] = lo;
      }
    }
    (void)ks;
  };

  ldA(0, 0);
  ldB(0, 0);
#pragma unroll
  for (int ks = 0; ks < KS; ++ks) {
    const int cur = ks & 1;
    if (ks + 1 < KS) {
      ldA(ks + 1, cur ^ 1);
      ldB(ks + 1, cur ^ 1);
    }
    cvtA(ks, cur);
#pragma unroll
    for (int mf = 0; mf < MF; ++mf) {
#pragma unroll
      for (int nf = 0; nf < NF; ++nf) {
        acc[mf][nf] = __builtin_amdgcn_mfma_f32_16x16x32_bf16(ah[cur][mf], bh[cur][nf], acc[mf][nf], 0, 0, 0);
        acc[mf][nf] = __builtin_amdgcn_mfma_f32_16x16x32_bf16(ah[cur][mf], bl[cur][nf], acc[mf][nf], 0, 0, 0);
        if (PRO == 2)
          acc[mf][nf] = __builtin_amdgcn_mfma_f32_16x16x32_bf16(al[cur][mf], bh[cur][nf], acc[mf][nf], 0, 0, 0);
      }
    }
  }

  // epilogue: C[row = bm+r0+mf*16+(l>>4)*4+rg][col = bo+c0+nf*16+lr]
  float s[NF], q[NF];
#pragma unroll
  for (int nf = 0; nf < NF; ++nf) { s[nf] = 0.f; q[nf] = 0.f; }
#pragma unroll
  for (int mf = 0; mf < MF; ++mf) {
    const int gr0 = bm + r0 + mf * 16 + (l >> 4) * 4;
#pragma unroll
    for (int nf = 0; nf < NF; ++nf) {
      const int gc = bo + c0 + nf * 16 + lr;
      float bval = 0.f;
      if (BIAS) bval = bias[gc];
#pragma unroll
      for (int rg = 0; rg < 4; ++rg) {
        const int row = gr0 + rg;
        if (row < N) {
          const float v = acc[mf][nf][rg] + bval;
          if (STATS) { s[nf] += v; q[nf] += v * v; }
          if (OUTBF)
            ((ushort*)Cout)[(size_t)row * O + gc] = f2bf_rne(v);
          else
            ((float*)Cout)[(size_t)row * O + gc] = v;
        }
      }
    }
  }

  if (STATS) {
    __shared__ float sred[4][NF][16][2];
#pragma unroll
    for (int nf = 0; nf < NF; ++nf) {
      s[nf] += __shfl_xor(s[nf], 16);
      s[nf] += __shfl_xor(s[nf], 32);
      q[nf] += __shfl_xor(q[nf], 16);
      q[nf] += __shfl_xor(q[nf], 32);
    }
    if (l < 16) {
#pragma unroll
      for (int nf = 0; nf < NF; ++nf) {
        sred[w][nf][l][0] = s[nf];
        sred[w][nf][l][1] = q[nf];
      }
    }
    __syncthreads();
    if (t < BN) {
      const int wcsel = (WC == 2) ? (t >> 6) : 0;
      const int nfi = (t >> 4) & 3;
      const int lri = t & 15;
      float S = 0.f, Q = 0.f;
#pragma unroll
      for (int ww = 0; ww < WR; ++ww) {
        const int w2 = ww * WC + wcsel;
        S += sred[w2][nfi][lri][0];
        Q += sred[w2][nfi][lri][1];
      }
      atomicAdd(&sums[bo + t], S);
      atomicAdd(&sums[O + bo + t], Q);
    }
  }
}

// ---------------------------------------------------------------- conv GEMM (BM=64, 4-wave)
// C[N,O] = lrelu(BN(A)) @ W * dis[row]  (bf16 out, no bias — agg adds it).
// 64x128 tile, 2x2 wave grid, grid (N/64, O/128): 2x block count of BM=128
// for occupancy while keeping MF=2 (16 MFMAs : 10 loads per wave-k-step).
// bl single-buffered to hold VGPR under the 4-blocks/CU ceiling.

template <int K>
__launch_bounds__(256, 4)
__global__ void k_gconv2(const ushort* __restrict__ A, const ushort* __restrict__ Whi,
                         const ushort* __restrict__ Wlo, const float* __restrict__ psums,
                         const float* __restrict__ pg, const float* __restrict__ pbb,
                         float invN, const float* __restrict__ rs, ushort* __restrict__ C,
                         int N, int O) {
  constexpr int KS = K / 32;
  constexpr int MF = 2, NF = 4;
  __shared__ float lcf[2 * K];

  const int bm = blockIdx.x * 64;
  const int bo = blockIdx.y * 128;
  const int t = threadIdx.x;
  const int w = t >> 6, l = t & 63;
  const int wr = w >> 1, wc = w & 1;
  const int r0 = wr * 32;
  const int c0 = wc * 64;
  const int lr = l & 15;
  const int lk = (l >> 4) * 8;

  if (t < K) {
    float sc, sh;
    bn_coeff(psums, pg, pbb, invN, K, t, sc, sh);
    lcf[t] = sc;
    lcf[K + t] = sh;
  }
  __syncthreads();

  f32x4 acc[MF][NF];
  const f32x4 zero4 = {0.f, 0.f, 0.f, 0.f};
#pragma unroll
  for (int mf = 0; mf < MF; ++mf)
#pragma unroll
    for (int nf = 0; nf < NF; ++nf) acc[mf][nf] = zero4;

  int arow[MF];
#pragma unroll
  for (int mf = 0; mf < MF; ++mf) {
    const int r = bm + r0 + mf * 16 + lr;
    arow[mf] = r < N ? r : N - 1;
  }

  short8 ar_[2][MF];  // raw A (bf16, pre-BN), double-buffered
  short8 ah[MF];      // converted operand (current step)
  short8 bh[2][NF];   // W-hi, double-buffered
  short8 bl[NF];      // W-lo, current step only

  auto ldA = [&](int ks, int b) {
#pragma unroll
    for (int mf = 0; mf < MF; ++mf)
      ar_[b][mf] = *reinterpret_cast<const short8*>(&A[(size_t)arow[mf] * K + ks * 32 + lk]);
  };
  auto ldB = [&](int ks, int b) {
#pragma unroll
    for (int nf = 0; nf < NF; ++nf)
      bh[b][nf] = *reinterpret_cast<const short8*>(
          &Whi[(size_t)(bo + c0 + nf * 16 + lr) * K + ks * 32 + lk]);
  };

  ldA(0, 0);
  ldB(0, 0);
#pragma unroll
  for (int ks = 0; ks < KS; ++ks) {
    const int cur = ks & 1;
    // lo-plane for THIS step, issued before next-step prefetch
#pragma unroll
    for (int nf = 0; nf < NF; ++nf)
      bl[nf] = *reinterpret_cast<const short8*>(
          &Wlo[(size_t)(bo + c0 + nf * 16 + lr) * K + ks * 32 + lk]);
    if (ks + 1 < KS) {
      ldA(ks + 1, cur ^ 1);
      ldB(ks + 1, cur ^ 1);
    }
    // BN + lrelu + bf16 pack (hidden under load latency)
    {
      const int k0 = ks * 32 + lk;
      const float4 c0v = *reinterpret_cast<const float4*>(&lcf[k0]);
      const float4 c1v = *reinterpret_cast<const float4*>(&lcf[k0 + 4]);
      const float4 h0v = *reinterpret_cast<const float4*>(&lcf[K + k0]);
      const float4 h1v = *reinterpret_cast<const float4*>(&lcf[K + k0 + 4]);
      const float sc[8] = {c0v.x, c0v.y, c0v.z, c0v.w, c1v.x, c1v.y, c1v.z, c1v.w};
      const float sh[8] = {h0v.x, h0v.y, h0v.z, h0v.w, h1v.x, h1v.y, h1v.z, h1v.w};
#pragma unroll
      for (int mf = 0; mf < MF; ++mf) {
        short8 hi;
#pragma unroll
        for (int j = 0; j < 8; ++j) {
          float x = bf2f((ushort)ar_[cur][mf][j]) * sc[j] + sh[j];
          x = x > 0.f ? x : 0.01f * x;
          hi[j] = (short)f2bf_rne(x);
        }
        ah[mf] = hi;
      }
    }
#pragma unroll
    for (int mf = 0; mf < MF; ++mf)
#pragma unroll
      for (int nf = 0; nf < NF; ++nf) {
        acc[mf][nf] = __builtin_amdgcn_mfma_f32_16x16x32_bf16(ah[mf], bh[cur][nf], acc[mf][nf], 0, 0, 0);
        acc[mf][nf] = __builtin_amdgcn_mfma_f32_16x16x32_bf16(ah[mf], bl[nf], acc[mf][nf], 0, 0, 0);
      }
  }

  // epilogue with row-scale (dis pre-scaling for aggregation)
#pragma unroll
  for (int mf = 0; mf < MF; ++mf) {
    const int rbase = bm + r0 + mf * 16 + (l >> 4) * 4;
    float rsv[4];
#pragma unroll
    for (int rg = 0; rg < 4; ++rg) {
      const int row = rbase + rg;
      rsv[rg] = (row < N) ? rs[row] : 0.f;
    }
#pragma unroll
    for (int nf = 0; nf < NF; ++nf) {
      const int gc = bo + c0 + nf * 16 + lr;
#pragma unroll
      for (int rg = 0; rg < 4; ++rg) {
        const int row = rbase + rg;
        if (row < N) C[(size_t)row * O + gc] = f2bf_rne(acc[mf][nf][rg] * rsv[rg]);
      }
    }
  }
}

// ---------------------------------------------------------------- bf16 column stats

template <int H>
__launch_bounds__(256)
__global__ void k_colstats_bf(const ushort* __restrict__ X, int n, float* __restrict__ sums) {
  constexpr int G = H / 8;
  constexpr int NS = 256 / G;
  const int t = threadIdx.x;
  const int cg = t % G;
  const int sub = t / G;
  const int r0 = blockIdx.x * 256;
  const int rend = (r0 + 256 < n) ? r0 + 256 : n;
  float s[8], q[8];
#pragma unroll
  for (int j = 0; j < 8; ++j) { s[j] = 0.f; q[j] = 0.f; }
  for (int r = r0 + sub; r < rend; r += NS) {
    const ushort8v u = *reinterpret_cast<const ushort8v*>(&X[(size_t)r * H + cg * 8]);
#pragma unroll
    for (int j = 0; j < 8; ++j) {
      const float f = bf2f(u[j]);
      s[j] += f;
      q[j] += f * f;
    }
  }
  __shared__ float red[256][16];
#pragma unroll
  for (int j = 0; j < 8; ++j) { red[t][j] = s[j]; red[t][8 + j] = q[j]; }
  __syncthreads();
  if (sub == 0) {
#pragma unroll
    for (int k = 1; k < NS; ++k) {
      const int u2 = cg + k * G;
#pragma unroll
      for (int j = 0; j < 8; ++j) { s[j] += red[u2][j]; q[j] += red[u2][8 + j]; }
    }
#pragma unroll
    for (int j = 0; j < 8; ++j) {
      atomicAdd(&sums[cg * 8 + j], s[j]);
      atomicAdd(&sums[H + cg * 8 + j], q[j]);
    }
  }
}

// ---------------------------------------------------------------- GCN aggregation
// Hin rows PRE-SCALED by dis:
//   out[d] = (sum_e Hin[col[e]] + Hin[d]) * dis[d] + bias
// 8-deep batched gathers, wave-uniform tail. COMBINE: fused residual
//   out = ((x*sc+sh) + r) * 2^-0.5 + x  (BN coeffs inline from raw sums).

template <int H, bool COMBINE>
__launch_bounds__(256)
__global__ void k_agg5(const ushort* __restrict__ Hin, const int* __restrict__ row_ptr,
                       const int* __restrict__ col, const float* __restrict__ dis,
                       const float* __restrict__ bias, const ushort* __restrict__ xin,
                       const float* __restrict__ bnsums, const float* __restrict__ g,
                       const float* __restrict__ bb, float invN,
                       ushort* __restrict__ out, int n) {
  constexpr int V = H / 64;  // 4 or 2
  const int lane = threadIdx.x & 63;
  const int node = blockIdx.x * 4 + (threadIdx.x >> 6);
  if (node >= n) return;
  const int lv = lane * V;
  const int beg = row_ptr[node];
  const int end = row_ptr[node + 1];

  float acc[V];
#pragma unroll
  for (int j = 0; j < V; ++j) acc[j] = 0.f;

  const int bend = beg + ((end - beg) & ~7);
  for (int e = beg; e < bend; e += 8) {
    int s8[8];
#pragma unroll
    for (int i = 0; i < 8; ++i) s8[i] = col[e + i];
    if constexpr (V == 4) {
      ushort4 u[8];
#pragma unroll
      for (int i = 0; i < 8; ++i)
        u[i] = *reinterpret_cast<const ushort4*>(&Hin[(size_t)s8[i] * H + lv]);
#pragma unroll
      for (int i = 0; i < 8; ++i) {
        acc[0] += bf2f(u[i].x); acc[1] += bf2f(u[i].y);
        acc[2] += bf2f(u[i].z); acc[3] += bf2f(u[i].w);
      }
    } else {
      ushort2 u[8];
#pragma unroll
      for (int i = 0; i < 8; ++i)
        u[i] = *reinterpret_cast<const ushort2*>(&Hin[(size_t)s8[i] * H + lv]);
#pragma unroll
      for (int i = 0; i < 8; ++i) {
        acc[0] += bf2f(u[i].x); acc[1] += bf2f(u[i].y);
      }
    }
  }
  // wave-uniform tail (<8 edges) + self row
  for (int e = bend; e <= end; ++e) {
    const int sidx = (e == end) ? node : col[e];
    if constexpr (V == 4) {
      const ushort4 u = *reinterpret_cast<const ushort4*>(&Hin[(size_t)sidx * H + lv]);
      acc[0] += bf2f(u.x); acc[1] += bf2f(u.y);
      acc[2] += bf2f(u.z); acc[3] += bf2f(u.w);
    } else {
      const ushort2 u = *reinterpret_cast<const ushort2*>(&Hin[(size_t)sidx * H + lv]);
      acc[0] += bf2f(u.x); acc[1] += bf2f(u.y);
    }
  }

  const float dd = dis[node];
  float r[V];
#pragma unroll
  for (int j = 0; j < V; ++j) r[j] = acc[j] * dd + bias[lv + j];

  if (COMBINE) {
    const float cinv = 0.70710678118654752f;
    const ushort* xp = &xin[(size_t)node * H + lv];
#pragma unroll
    for (int j = 0; j < V; ++j) {
      const float x = bf2f(xp[j]);
      float sc, sh;
      bn_coeff(bnsums, g, bb, invN, H, lv + j, sc, sh);
      r[j] = (x * sc + sh + r[j]) * cinv + x;
    }
  }

  if constexpr (V == 4) {
    ushort4 o;
    o.x = f2bf_rne(r[0]); o.y = f2bf_rne(r[1]);
    o.z = f2bf_rne(r[2]); o.w = f2bf_rne(r[3]);
    *reinterpret_cast<ushort4*>(&out[(size_t)node * H + lv]) = o;
  } else {
    ushort2 o;
    o.x = f2bf_rne(r[0]); o.y = f2bf_rne(r[1]);
    *reinterpret_cast<ushort2*>(&out[(size_t)node * H + lv]) = o;
  }
}

// ---------------------------------------------------------------- launch

extern "C" void kernel_launch(void* const* d_in, const int* in_sizes, int n_in,
                              void* d_out, int out_size, void* d_ws, size_t ws_size,
                              hipStream_t stream) {
  const int N = in_sizes[0] / 128;
  const int E = in_sizes[1] / 2;

  const float* x_vert = (const float*)d_in[0];
  const int* src = (const int*)d_in[1];
  const int* dst = src + E;
  const float* g1_lin_W = (const float*)d_in[2];
  const float* g1_lin_b = (const float*)d_in[3];
  const float* g1_c1_W = (const float*)d_in[4];
  const float* g1_c1_b = (const float*)d_in[5];
  const float* g1_c2_W = (const float*)d_in[6];
  const float* g1_c2_b = (const float*)d_in[7];
  const float* g1_n1_g = (const float*)d_in[8];
  const float* g1_n1_b = (const float*)d_in[9];
  const float* g1_n2_g = (const float*)d_in[10];
  const float* g1_n2_b = (const float*)d_in[11];
  const float* g2_lin_W = (const float*)d_in[12];
  const float* g2_lin_b = (const float*)d_in[13];
  const float* g2_c1_W = (const float*)d_in[14];
  const float* g2_c1_b = (const float*)d_in[15];
  const float* g2_c2_W = (const float*)d_in[16];
  const float* g2_c2_b = (const float*)d_in[17];
  const float* g2_n1_g = (const float*)d_in[18];
  const float* g2_n1_b = (const float*)d_in[19];
  const float* g2_n2_g = (const float*)d_in[20];
  const float* g2_n2_b = (const float*)d_in[21];
  const float* out_W = (const float*)d_in[22];
  const float* out_b = (const float*)d_in[23];
  const float* n1_g = (const float*)d_in[24];
  const float* n1_b = (const float*)d_in[25];
  const float* l1_W = (const float*)d_in[26];
  const float* l1_b = (const float*)d_in[27];
  const float* n2_g = (const float*)d_in[28];
  const float* n2_b = (const float*)d_in[29];
  const float* l2_W = (const float*)d_in[30];
  const float* l2_b = (const float*)d_in[31];

  float* out = (float*)d_out;

  // ---- workspace carve-up
  size_t off = 0;
  auto alloc = [&](size_t bytes) -> void* {
    void* p = (char*)d_ws + off;
    off += (bytes + 255) & ~(size_t)255;
    return p;
  };
  ushort* B1 = (ushort*)alloc((size_t)N * 256 * 2);  // x_in block1 (bf16 residual src)
  ushort* B2 = (ushort*)alloc((size_t)N * 128 * 2);  // x_in block2 (bf16 residual src)
  ushort* sA = (ushort*)alloc((size_t)N * 256 * 2);  // rotating bf16 slot A
  ushort* sB = (ushort*)alloc((size_t)N * 256 * 2);  // rotating bf16 slot B
  int* cnt = (int*)alloc((size_t)N * 4);
  int* row_ptr = (int*)alloc((size_t)(N + 1) * 4);
  int* cursor = (int*)alloc((size_t)N * 4);
  int* col = (int*)alloc((size_t)E * 4);
  int* part = (int*)alloc(1024 * 4);
  float* dis = (float*)alloc((size_t)N * 4);
  float* sums = (float*)alloc(6 * 512 * 4);

  const int wk[9] = {128, 256, 256, 256, 128, 128, 128, 128, 64};
  const int wo[9] = {256, 256, 256, 128, 128, 128, 128, 64, 64};
  const float* wsrc[9] = {g1_lin_W, g1_c1_W, g1_c2_W, g2_lin_W, g2_c1_W,
                          g2_c2_W, out_W, l1_W, l2_W};
  ushort* whi[9];
  ushort* wlo[9];
  for (int i = 0; i < 9; ++i) {
    whi[i] = (ushort*)alloc((size_t)wk[i] * wo[i] * 2);
    wlo[i] = (ushort*)alloc((size_t)wk[i] * wo[i] * 2);
  }
  (void)ws_size;
  (void)n_in;
  (void)out_size;

  const int NB = IDIV(N, 256);
  const int GM = IDIV(N, 128);
  const int G64 = IDIV(N, 64);
  const float invN = 1.0f / (float)N;
  float* sums0 = sums + 0 * 512;
  float* sums1 = sums + 1 * 512;
  float* sums2 = sums + 2 * 512;
  float* sums3 = sums + 3 * 512;
  float* sums4 = sums + 4 * 512;
  float* sums5 = sums + 5 * 512;

  // ---- CSR build + weight prep
  k_zero_i32<<<NB, 256, 0, stream>>>(cnt, N);
  k_zero_f32<<<IDIV(6 * 512, 256), 256, 0, stream>>>(sums, 6 * 512);
  {
    WPack p;
    for (int i = 0; i < 9; ++i) p.s[i] = WSpec{wsrc[i], whi[i], wlo[i], wk[i], wo[i]};
    k_wprep<<<dim3(64, 9), 256, 0, stream>>>(p);
  }
  k_count<<<IDIV(E, 256), 256, 0, stream>>>(dst, E, cnt);
  k_scan_partial<<<NB, 256, 0, stream>>>(cnt, N, part);
  k_scan_offsets<<<1, 256, 0, stream>>>(part, NB);
  k_scan_final<<<NB, 256, 0, stream>>>(cnt, N, part, row_ptr);
  k_cursor_dis<<<NB, 256, 0, stream>>>(row_ptr, cnt, cursor, dis, row_ptr + N, N, E);
  k_scatter<<<IDIV(E, 256), 256, 0, stream>>>(src, dst, E, cursor, col);

  // ================= block 1 (in 128, hid 256) =================
  k_gemm4<128, 256, 1, true, true, true><<<dim3(GM, 2), 256, 0, stream>>>(
      x_vert, whi[0], wlo[0], g1_lin_b, nullptr, nullptr, nullptr, 0.f, B1, sums0, N);
  k_gconv2<256><<<dim3(G64, 2), 256, 0, stream>>>(
      B1, whi[1], wlo[1], sums0, g1_n1_g, g1_n1_b, invN, dis, sB, N, 256);
  k_agg5<256, false><<<IDIV(N, 4), 256, 0, stream>>>(
      sB, row_ptr, col, dis, g1_c1_b, nullptr, nullptr, nullptr, nullptr, 0.f, sA, N);
  k_colstats_bf<256><<<NB, 256, 0, stream>>>(sA, N, sums1);
  k_gconv2<256><<<dim3(G64, 2), 256, 0, stream>>>(
      sA, whi[2], wlo[2], sums1, g1_n2_g, g1_n2_b, invN, dis, sB, N, 256);
  k_agg5<256, true><<<IDIV(N, 4), 256, 0, stream>>>(
      sB, row_ptr, col, dis, g1_c2_b, B1, sums0, g1_n1_g, g1_n1_b, invN, sA, N);

  // ================= block 2 (in 256, hid 128) =================
  k_gemm4<256, 128, 0, true, true, true><<<dim3(GM, 1), 256, 0, stream>>>(
      sA, whi[3], wlo[3], g2_lin_b, nullptr, nullptr, nullptr, 0.f, B2, sums2, N);
  k_gconv2<128><<<dim3(G64, 1), 256, 0, stream>>>(
      B2, whi[4], wlo[4], sums2, g2_n1_g, g2_n1_b, invN, dis, sB, N, 128);
  k_agg5<128, false><<<IDIV(N, 4), 256, 0, stream>>>(
      sB, row_ptr, col, dis, g2_c1_b, nullptr, nullptr, nullptr, nullptr, 0.f, sA, N);
  k_colstats_bf<128><<<NB, 256, 0, stream>>>(sA, N, sums3);
  k_gconv2<128><<<dim3(G64, 1), 256, 0, stream>>>(
      sA, whi[5], wlo[5], sums3, g2_n2_g, g2_n2_b, invN, dis, sB, N, 128);
  k_agg5<128, true><<<IDIV(N, 4), 256, 0, stream>>>(
      sB, row_ptr, col, dis, g2_c2_b, B2, sums2, g2_n1_g, g2_n1_b, invN, sA, N);

  // ================= head =================
  k_gemm4<128, 128, 0, true, true, true><<<dim3(GM, 1), 256, 0, stream>>>(
      sA, whi[6], wlo[6], out_b, nullptr, nullptr, nullptr, 0.f, sB, sums4, N);
  k_gemm4<128, 64, 2, true, true, true><<<dim3(GM, 1), 256, 0, stream>>>(
      sB, whi[7], wlo[7], l1_b, sums4, n1_g, n1_b, invN, sA, sums5, N);
  k_gemm4<64, 64, 2, false, false, true><<<dim3(GM, 1), 256, 0, stream>>>(
      sA, whi[8], wlo[8], l2_b, sums5, n2_g, n2_b, invN, out, nullptr, N);
}

// Round 11
// 625.401 us; speedup vs baseline: 1.2273x; 1.2273x over previous
//
#include <hip/hip_runtime.h>
#include <cstddef>
#include <cstdint>

#define IDIV(a, b) (((a) + (b) - 1) / (b))

typedef __attribute__((ext_vector_type(8))) short short8;
typedef __attribute__((ext_vector_type(8))) unsigned short ushort8v;
typedef __attribute__((ext_vector_type(4))) float f32x4;

__device__ inline ushort f2bf_rne(float x) {
  uint32_t u = __builtin_bit_cast(uint32_t, x);
  u += 0x7fff + ((u >> 16) & 1);
  return (ushort)(u >> 16);
}
__device__ inline float bf2f(ushort h) {
  uint32_t u = (uint32_t)h << 16;
  return __builtin_bit_cast(float, u);
}

// BN coefficients from raw sums
__device__ inline void bn_coeff(const float* __restrict__ sums, const float* __restrict__ g,
                                const float* __restrict__ bb, float invN, int H, int c,
                                float& sc, float& sh) {
  const float mean = sums[c] * invN;
  float var = sums[H + c] * invN - mean * mean;
  var = var < 0.f ? 0.f : var;
  sc = g[c] * rsqrtf(var + 1e-5f);
  sh = bb[c] - mean * sc;
}

// ---------------------------------------------------------------- utilities

__global__ void k_zero_i32(int* __restrict__ p, int n) {
  int i = blockIdx.x * blockDim.x + threadIdx.x;
  if (i < n) p[i] = 0;
}

__global__ void k_zero_f32(float* __restrict__ p, int n) {
  int i = blockIdx.x * blockDim.x + threadIdx.x;
  if (i < n) p[i] = 0.f;
}

// ---------------------------------------------------------------- CSR build

__global__ void k_count(const int* __restrict__ dst, int E, int* __restrict__ cnt) {
  int i = blockIdx.x * blockDim.x + threadIdx.x;
  if (i < E) atomicAdd(&cnt[dst[i]], 1);
}

__global__ void k_scan_partial(const int* __restrict__ cnt, int n, int* __restrict__ part) {
  __shared__ int sm[256];
  const int t = threadIdx.x;
  const int i = blockIdx.x * 256 + t;
  sm[t] = (i < n) ? cnt[i] : 0;
  __syncthreads();
  for (int off = 128; off > 0; off >>= 1) {
    if (t < off) sm[t] += sm[t + off];
    __syncthreads();
  }
  if (t == 0) part[blockIdx.x] = sm[0];
}

__global__ void k_scan_offsets(int* __restrict__ part, int nb) {
  __shared__ int sm[256];
  const int t = threadIdx.x;
  if (t < nb) sm[t] = part[t];
  __syncthreads();
  if (t == 0) {
    int run = 0;
    for (int i = 0; i < nb; ++i) { int v = sm[i]; sm[i] = run; run += v; }
  }
  __syncthreads();
  if (t < nb) part[t] = sm[t];
}

__global__ void k_scan_final(const int* __restrict__ cnt, int n, const int* __restrict__ part,
                             int* __restrict__ row_ptr) {
  __shared__ int sm[256];
  const int t = threadIdx.x;
  const int i = blockIdx.x * 256 + t;
  const int v = (i < n) ? cnt[i] : 0;
  sm[t] = v;
  __syncthreads();
  for (int off = 1; off < 256; off <<= 1) {
    int x = (t >= off) ? sm[t - off] : 0;
    __syncthreads();
    sm[t] += x;
    __syncthreads();
  }
  if (i < n) row_ptr[i] = part[blockIdx.x] + sm[t] - v;  // exclusive scan
}

__global__ void k_cursor_dis(const int* __restrict__ row_ptr, const int* __restrict__ cnt,
                             int* __restrict__ cursor, float* __restrict__ dis,
                             int* __restrict__ row_ptr_end, int n, int E) {
  int i = blockIdx.x * blockDim.x + threadIdx.x;
  if (i == 0) *row_ptr_end = E;
  if (i < n) {
    cursor[i] = row_ptr[i];
    dis[i] = rsqrtf((float)cnt[i] + 1.0f);
  }
}

__global__ void k_scatter(const int* __restrict__ src, const int* __restrict__ dst, int E,
                          int* __restrict__ cursor, int* __restrict__ col) {
  int i = blockIdx.x * blockDim.x + threadIdx.x;
  if (i < E) {
    int d = dst[i];
    int pos = atomicAdd(&cursor[d], 1);
    col[pos] = src[i];
  }
}

// ---------------------------------------------------------------- weight prep
// W[K][O] fp32 -> Wt_hi[O][K], Wt_lo[O][K] bf16 (transposed + hi/lo split)

struct WSpec { const float* W; ushort* hi; ushort* lo; int K; int O; };
struct WPack { WSpec s[9]; };

__global__ void k_wprep(WPack p) {
  const WSpec w = p.s[blockIdx.y];
  const int total = w.K * w.O;
  for (int i = blockIdx.x * 256 + threadIdx.x; i < total; i += gridDim.x * 256) {
    const int o = i / w.K;
    const int k = i - o * w.K;
    const float v = w.W[(size_t)k * w.O + o];
    const ushort h = f2bf_rne(v);
    w.hi[i] = h;
    w.lo[i] = f2bf_rne(v - bf2f(h));
  }
}

// ---------------------------------------------------------------- unified MFMA GEMM
// C[N,O] = op(A)[N,K] @ W[K,O] (+bias)(*rowscale). BM=256, BN=64, 8 waves.
// W panel (hi+lo, full K) staged in LDS ONCE per block -> inner loop is
// ds_read_b128 + MFMA; only streaming A-loads (depth-1 prefetch) touch global.
// LDS rows padded to K+8 shorts (528B stride @K=256 -> ~2-way bank alias).
// PRO: 0 = A bf16 passthrough; 1 = A fp32 -> bf16; 2 = A bf16, BN+lrelu
// (coeff table in LDS from raw sums). ASPLIT: on-the-fly A hi/lo (3 MFMAs).
// STATS: fused col sum/sumsq (pre-rowscale). RS: scale row by rs[row].

template <int K, int O, int PRO, bool ASPLIT, bool STATS, bool OUTBF, bool BIAS, bool RS>
__launch_bounds__(512, 4)
__global__ void k_gemm5(const void* __restrict__ Av, const ushort* __restrict__ Whi,
                        const ushort* __restrict__ Wlo, const float* __restrict__ bias,
                        const float* __restrict__ psums, const float* __restrict__ pg,
                        const float* __restrict__ pbb, float invN,
                        const float* __restrict__ rs, void* __restrict__ Cout,
                        float* __restrict__ sums, int N) {
  constexpr int KS = K / 32;
  constexpr int KP = K + 8;  // padded LDS row (shorts)
  constexpr int MF = 2, NF = 4;

  const ushort* Ab = (const ushort*)Av;
  const float* Af = (const float*)Av;

  __shared__ ushort Ws[2][64][KP];
  __shared__ float lcf[(PRO == 2) ? 2 * K : 2];
  __shared__ float sred[STATS ? 8 : 1][NF][16][2];

  const int bm = blockIdx.x * 256;
  const int bo = blockIdx.y * 64;
  const int t = threadIdx.x;
  const int w = t >> 6, l = t & 63;
  const int lr = l & 15;
  const int lk = (l >> 4) * 8;

  if constexpr (PRO == 2) {
    for (int c = t; c < K; c += 512) {
      float sc, sh;
      bn_coeff(psums, pg, pbb, invN, K, c, sc, sh);
      lcf[c] = sc;
      lcf[K + c] = sh;
    }
  }
  // ---- stage W panel (both planes) into LDS
  {
    constexpr int CPR = K / 8;            // 16B chunks per row
    constexpr int CHUNKS = 2 * 64 * CPR;  // total chunks
    for (int i = t; i < CHUNKS; i += 512) {
      const int plane = i / (64 * CPR);
      const int rem = i - plane * 64 * CPR;
      const int row = rem / CPR;
      const int kc = (rem - row * CPR) * 8;
      const ushort* sp = plane ? Wlo : Whi;
      *reinterpret_cast<ushort8v*>(&Ws[plane][row][kc]) =
          *reinterpret_cast<const ushort8v*>(&sp[(size_t)(bo + row) * K + kc]);
    }
  }
  __syncthreads();

  f32x4 acc[MF][NF];
  const f32x4 zero4 = {0.f, 0.f, 0.f, 0.f};
#pragma unroll
  for (int mf = 0; mf < MF; ++mf)
#pragma unroll
    for (int nf = 0; nf < NF; ++nf) acc[mf][nf] = zero4;

  int arow[MF];
#pragma unroll
  for (int mf = 0; mf < MF; ++mf) {
    const int r = bm + w * 32 + mf * 16 + lr;
    arow[mf] = r < N ? r : N - 1;
  }

  short8 ar_[2][MF];
  float4 rawf[2][MF][2];
  short8 ah[MF], al_[MF];

  auto ldA = [&](int ks, int b) {
#pragma unroll
    for (int mf = 0; mf < MF; ++mf) {
      const size_t base = (size_t)arow[mf] * K + ks * 32 + lk;
      if constexpr (PRO == 1) {
        rawf[b][mf][0] = *reinterpret_cast<const float4*>(&Af[base]);
        rawf[b][mf][1] = *reinterpret_cast<const float4*>(&Af[base + 4]);
      } else {
        ar_[b][mf] = *reinterpret_cast<const short8*>(&Ab[base]);
      }
    }
  };
  auto cvtA = [&](int ks, int b) {
    if constexpr (PRO == 0) {
#pragma unroll
      for (int mf = 0; mf < MF; ++mf) ah[mf] = ar_[b][mf];
    } else if constexpr (PRO == 1) {
#pragma unroll
      for (int mf = 0; mf < MF; ++mf) {
        const float f[8] = {rawf[b][mf][0].x, rawf[b][mf][0].y, rawf[b][mf][0].z,
                            rawf[b][mf][0].w, rawf[b][mf][1].x, rawf[b][mf][1].y,
                            rawf[b][mf][1].z, rawf[b][mf][1].w};
        short8 hi;
#pragma unroll
        for (int j = 0; j < 8; ++j) hi[j] = (short)f2bf_rne(f[j]);
        ah[mf] = hi;
      }
    } else {
      const int k0 = ks * 32 + lk;
      const float4 c0v = *reinterpret_cast<const float4*>(&lcf[k0]);
      const float4 c1v = *reinterpret_cast<const float4*>(&lcf[k0 + 4]);
      const float4 h0v = *reinterpret_cast<const float4*>(&lcf[K + k0]);
      const float4 h1v = *reinterpret_cast<const float4*>(&lcf[K + k0 + 4]);
      const float sc[8] = {c0v.x, c0v.y, c0v.z, c0v.w, c1v.x, c1v.y, c1v.z, c1v.w};
      const float sh[8] = {h0v.x, h0v.y, h0v.z, h0v.w, h1v.x, h1v.y, h1v.z, h1v.w};
#pragma unroll
      for (int mf = 0; mf < MF; ++mf) {
        float f[8];
#pragma unroll
        for (int j = 0; j < 8; ++j) {
          float x = bf2f((ushort)ar_[b][mf][j]) * sc[j] + sh[j];
          f[j] = x > 0.f ? x : 0.01f * x;
        }
        short8 hi, lo;
#pragma unroll
        for (int j = 0; j < 8; ++j) {
          const ushort h = f2bf_rne(f[j]);
          hi[j] = (short)h;
          lo[j] = (short)f2bf_rne(f[j] - bf2f(h));
        }
        ah[mf] = hi;
        if (ASPLIT) al_[mf] = lo;
      }
    }
  };

  ldA(0, 0);
#pragma unroll
  for (int ks = 0; ks < KS; ++ks) {
    const int cur = ks & 1;
    if (ks + 1 < KS) ldA(ks + 1, cur ^ 1);
    cvtA(ks, cur);
#pragma unroll
    for (int nf = 0; nf < NF; ++nf) {
      const short8 bhf = *reinterpret_cast<const short8*>(&Ws[0][nf * 16 + lr][ks * 32 + lk]);
      const short8 blf = *reinterpret_cast<const short8*>(&Ws[1][nf * 16 + lr][ks * 32 + lk]);
#pragma unroll
      for (int mf = 0; mf < MF; ++mf) {
        acc[mf][nf] = __builtin_amdgcn_mfma_f32_16x16x32_bf16(ah[mf], bhf, acc[mf][nf], 0, 0, 0);
        acc[mf][nf] = __builtin_amdgcn_mfma_f32_16x16x32_bf16(ah[mf], blf, acc[mf][nf], 0, 0, 0);
        if (ASPLIT)
          acc[mf][nf] = __builtin_amdgcn_mfma_f32_16x16x32_bf16(al_[mf], bhf, acc[mf][nf], 0, 0, 0);
      }
    }
  }

  // ---- epilogue: C[row = bm + w*32 + mf*16 + (l>>4)*4 + rg][col = bo + nf*16 + lr]
  float s[NF], q[NF];
#pragma unroll
  for (int nf = 0; nf < NF; ++nf) { s[nf] = 0.f; q[nf] = 0.f; }
#pragma unroll
  for (int mf = 0; mf < MF; ++mf) {
    const int gr0 = bm + w * 32 + mf * 16 + (l >> 4) * 4;
    float rsv[4];
#pragma unroll
    for (int rg = 0; rg < 4; ++rg) {
      const int row = gr0 + rg;
      rsv[rg] = (RS && row < N) ? rs[row] : 0.f;
    }
#pragma unroll
    for (int nf = 0; nf < NF; ++nf) {
      const int gc = bo + nf * 16 + lr;
      float bval = 0.f;
      if (BIAS) bval = bias[gc];
#pragma unroll
      for (int rg = 0; rg < 4; ++rg) {
        const int row = gr0 + rg;
        if (row < N) {
          float v = acc[mf][nf][rg] + bval;
          if (STATS) { s[nf] += v; q[nf] += v * v; }
          if (RS) v *= rsv[rg];
          if (OUTBF)
            ((ushort*)Cout)[(size_t)row * O + gc] = f2bf_rne(v);
          else
            ((float*)Cout)[(size_t)row * O + gc] = v;
        }
      }
    }
  }

  if (STATS) {
#pragma unroll
    for (int nf = 0; nf < NF; ++nf) {
      s[nf] += __shfl_xor(s[nf], 16);
      s[nf] += __shfl_xor(s[nf], 32);
      q[nf] += __shfl_xor(q[nf], 16);
      q[nf] += __shfl_xor(q[nf], 32);
    }
    if (l < 16) {
#pragma unroll
      for (int nf = 0; nf < NF; ++nf) {
        sred[w][nf][l][0] = s[nf];
        sred[w][nf][l][1] = q[nf];
      }
    }
    __syncthreads();
    if (t < 64) {
      const int nfi = t >> 4;
      const int lri = t & 15;
      float S = 0.f, Q = 0.f;
#pragma unroll
      for (int ww = 0; ww < 8; ++ww) {
        S += sred[ww][nfi][lri][0];
        Q += sred[ww][nfi][lri][1];
      }
      atomicAdd(&sums[bo + t], S);
      atomicAdd(&sums[O + bo + t], Q);
    }
  }
}

// ---------------------------------------------------------------- bf16 column stats

template <int H>
__launch_bounds__(256)
__global__ void k_colstats_bf(const ushort* __restrict__ X, int n, float* __restrict__ sums) {
  constexpr int G = H / 8;
  constexpr int NS = 256 / G;
  const int t = threadIdx.x;
  const int cg = t % G;
  const int sub = t / G;
  const int r0 = blockIdx.x * 256;
  const int rend = (r0 + 256 < n) ? r0 + 256 : n;
  float s[8], q[8];
#pragma unroll
  for (int j = 0; j < 8; ++j) { s[j] = 0.f; q[j] = 0.f; }
  for (int r = r0 + sub; r < rend; r += NS) {
    const ushort8v u = *reinterpret_cast<const ushort8v*>(&X[(size_t)r * H + cg * 8]);
#pragma unroll
    for (int j = 0; j < 8; ++j) {
      const float f = bf2f(u[j]);
      s[j] += f;
      q[j] += f * f;
    }
  }
  __shared__ float red[256][16];
#pragma unroll
  for (int j = 0; j < 8; ++j) { red[t][j] = s[j]; red[t][8 + j] = q[j]; }
  __syncthreads();
  if (sub == 0) {
#pragma unroll
    for (int k = 1; k < NS; ++k) {
      const int u2 = cg + k * G;
#pragma unroll
      for (int j = 0; j < 8; ++j) { s[j] += red[u2][j]; q[j] += red[u2][8 + j]; }
    }
#pragma unroll
    for (int j = 0; j < 8; ++j) {
      atomicAdd(&sums[cg * 8 + j], s[j]);
      atomicAdd(&sums[H + cg * 8 + j], q[j]);
    }
  }
}

// ---------------------------------------------------------------- GCN aggregation
// Hin rows PRE-SCALED by dis:
//   out[d] = (sum_e Hin[col[e]] + Hin[d]) * dis[d] + bias
// 8-deep batched gathers, wave-uniform tail. COMBINE: fused residual
//   out = ((x*sc+sh) + r) * 2^-0.5 + x  (BN coeffs inline from raw sums).

template <int H, bool COMBINE>
__launch_bounds__(256)
__global__ void k_agg5(const ushort* __restrict__ Hin, const int* __restrict__ row_ptr,
                       const int* __restrict__ col, const float* __restrict__ dis,
                       const float* __restrict__ bias, const ushort* __restrict__ xin,
                       const float* __restrict__ bnsums, const float* __restrict__ g,
                       const float* __restrict__ bb, float invN,
                       ushort* __restrict__ out, int n) {
  constexpr int V = H / 64;  // 4 or 2
  const int lane = threadIdx.x & 63;
  const int node = blockIdx.x * 4 + (threadIdx.x >> 6);
  if (node >= n) return;
  const int lv = lane * V;
  const int beg = row_ptr[node];
  const int end = row_ptr[node + 1];

  float acc[V];
#pragma unroll
  for (int j = 0; j < V; ++j) acc[j] = 0.f;

  const int bend = beg + ((end - beg) & ~7);
  for (int e = beg; e < bend; e += 8) {
    int s8[8];
#pragma unroll
    for (int i = 0; i < 8; ++i) s8[i] = col[e + i];
    if constexpr (V == 4) {
      ushort4 u[8];
#pragma unroll
      for (int i = 0; i < 8; ++i)
        u[i] = *reinterpret_cast<const ushort4*>(&Hin[(size_t)s8[i] * H + lv]);
#pragma unroll
      for (int i = 0; i < 8; ++i) {
        acc[0] += bf2f(u[i].x); acc[1] += bf2f(u[i].y);
        acc[2] += bf2f(u[i].z); acc[3] += bf2f(u[i].w);
      }
    } else {
      ushort2 u[8];
#pragma unroll
      for (int i = 0; i < 8; ++i)
        u[i] = *reinterpret_cast<const ushort2*>(&Hin[(size_t)s8[i] * H + lv]);
#pragma unroll
      for (int i = 0; i < 8; ++i) {
        acc[0] += bf2f(u[i].x); acc[1] += bf2f(u[i].y);
      }
    }
  }
  // wave-uniform tail (<8 edges) + self row
  for (int e = bend; e <= end; ++e) {
    const int sidx = (e == end) ? node : col[e];
    if constexpr (V == 4) {
      const ushort4 u = *reinterpret_cast<const ushort4*>(&Hin[(size_t)sidx * H + lv]);
      acc[0] += bf2f(u.x); acc[1] += bf2f(u.y);
      acc[2] += bf2f(u.z); acc[3] += bf2f(u.w);
    } else {
      const ushort2 u = *reinterpret_cast<const ushort2*>(&Hin[(size_t)sidx * H + lv]);
      acc[0] += bf2f(u.x); acc[1] += bf2f(u.y);
    }
  }

  const float dd = dis[node];
  float r[V];
#pragma unroll
  for (int j = 0; j < V; ++j) r[j] = acc[j] * dd + bias[lv + j];

  if (COMBINE) {
    const float cinv = 0.70710678118654752f;
    const ushort* xp = &xin[(size_t)node * H + lv];
#pragma unroll
    for (int j = 0; j < V; ++j) {
      const float x = bf2f(xp[j]);
      float sc, sh;
      bn_coeff(bnsums, g, bb, invN, H, lv + j, sc, sh);
      r[j] = (x * sc + sh + r[j]) * cinv + x;
    }
  }

  if constexpr (V == 4) {
    ushort4 o;
    o.x = f2bf_rne(r[0]); o.y = f2bf_rne(r[1]);
    o.z = f2bf_rne(r[2]); o.w = f2bf_rne(r[3]);
    *reinterpret_cast<ushort4*>(&out[(size_t)node * H + lv]) = o;
  } else {
    ushort2 o;
    o.x = f2bf_rne(r[0]); o.y = f2bf_rne(r[1]);
    *reinterpret_cast<ushort2*>(&out[(size_t)node * H + lv]) = o;
  }
}

// ---------------------------------------------------------------- launch

extern "C" void kernel_launch(void* const* d_in, const int* in_sizes, int n_in,
                              void* d_out, int out_size, void* d_ws, size_t ws_size,
                              hipStream_t stream) {
  const int N = in_sizes[0] / 128;
  const int E = in_sizes[1] / 2;

  const float* x_vert = (const float*)d_in[0];
  const int* src = (const int*)d_in[1];
  const int* dst = src + E;
  const float* g1_lin_W = (const float*)d_in[2];
  const float* g1_lin_b = (const float*)d_in[3];
  const float* g1_c1_W = (const float*)d_in[4];
  const float* g1_c1_b = (const float*)d_in[5];
  const float* g1_c2_W = (const float*)d_in[6];
  const float* g1_c2_b = (const float*)d_in[7];
  const float* g1_n1_g = (const float*)d_in[8];
  const float* g1_n1_b = (const float*)d_in[9];
  const float* g1_n2_g = (const float*)d_in[10];
  const float* g1_n2_b = (const float*)d_in[11];
  const float* g2_lin_W = (const float*)d_in[12];
  const float* g2_lin_b = (const float*)d_in[13];
  const float* g2_c1_W = (const float*)d_in[14];
  const float* g2_c1_b = (const float*)d_in[15];
  const float* g2_c2_W = (const float*)d_in[16];
  const float* g2_c2_b = (const float*)d_in[17];
  const float* g2_n1_g = (const float*)d_in[18];
  const float* g2_n1_b = (const float*)d_in[19];
  const float* g2_n2_g = (const float*)d_in[20];
  const float* g2_n2_b = (const float*)d_in[21];
  const float* out_W = (const float*)d_in[22];
  const float* out_b = (const float*)d_in[23];
  const float* n1_g = (const float*)d_in[24];
  const float* n1_b = (const float*)d_in[25];
  const float* l1_W = (const float*)d_in[26];
  const float* l1_b = (const float*)d_in[27];
  const float* n2_g = (const float*)d_in[28];
  const float* n2_b = (const float*)d_in[29];
  const float* l2_W = (const float*)d_in[30];
  const float* l2_b = (const float*)d_in[31];

  float* out = (float*)d_out;

  // ---- workspace carve-up
  size_t off = 0;
  auto alloc = [&](size_t bytes) -> void* {
    void* p = (char*)d_ws + off;
    off += (bytes + 255) & ~(size_t)255;
    return p;
  };
  ushort* B1 = (ushort*)alloc((size_t)N * 256 * 2);  // x_in block1 (bf16 residual src)
  ushort* B2 = (ushort*)alloc((size_t)N * 128 * 2);  // x_in block2 (bf16 residual src)
  ushort* sA = (ushort*)alloc((size_t)N * 256 * 2);  // rotating bf16 slot A
  ushort* sB = (ushort*)alloc((size_t)N * 256 * 2);  // rotating bf16 slot B
  int* cnt = (int*)alloc((size_t)N * 4);
  int* row_ptr = (int*)alloc((size_t)(N + 1) * 4);
  int* cursor = (int*)alloc((size_t)N * 4);
  int* col = (int*)alloc((size_t)E * 4);
  int* part = (int*)alloc(1024 * 4);
  float* dis = (float*)alloc((size_t)N * 4);
  float* sums = (float*)alloc(6 * 512 * 4);

  const int wk[9] = {128, 256, 256, 256, 128, 128, 128, 128, 64};
  const int wo[9] = {256, 256, 256, 128, 128, 128, 128, 64, 64};
  const float* wsrc[9] = {g1_lin_W, g1_c1_W, g1_c2_W, g2_lin_W, g2_c1_W,
                          g2_c2_W, out_W, l1_W, l2_W};
  ushort* whi[9];
  ushort* wlo[9];
  for (int i = 0; i < 9; ++i) {
    whi[i] = (ushort*)alloc((size_t)wk[i] * wo[i] * 2);
    wlo[i] = (ushort*)alloc((size_t)wk[i] * wo[i] * 2);
  }
  (void)ws_size;
  (void)n_in;
  (void)out_size;

  const int NB = IDIV(N, 256);
  const int GT = IDIV(N, 256);  // BM=256 grid x
  const float invN = 1.0f / (float)N;
  float* sums0 = sums + 0 * 512;
  float* sums1 = sums + 1 * 512;
  float* sums2 = sums + 2 * 512;
  float* sums3 = sums + 3 * 512;
  float* sums4 = sums + 4 * 512;
  float* sums5 = sums + 5 * 512;

  // ---- CSR build + weight prep
  k_zero_i32<<<NB, 256, 0, stream>>>(cnt, N);
  k_zero_f32<<<IDIV(6 * 512, 256), 256, 0, stream>>>(sums, 6 * 512);
  {
    WPack p;
    for (int i = 0; i < 9; ++i) p.s[i] = WSpec{wsrc[i], whi[i], wlo[i], wk[i], wo[i]};
    k_wprep<<<dim3(64, 9), 256, 0, stream>>>(p);
  }
  k_count<<<IDIV(E, 256), 256, 0, stream>>>(dst, E, cnt);
  k_scan_partial<<<NB, 256, 0, stream>>>(cnt, N, part);
  k_scan_offsets<<<1, 256, 0, stream>>>(part, NB);
  k_scan_final<<<NB, 256, 0, stream>>>(cnt, N, part, row_ptr);
  k_cursor_dis<<<NB, 256, 0, stream>>>(row_ptr, cnt, cursor, dis, row_ptr + N, N, E);
  k_scatter<<<IDIV(E, 256), 256, 0, stream>>>(src, dst, E, cursor, col);

  // ================= block 1 (in 128, hid 256) =================
  k_gemm5<128, 256, 1, false, true, true, true, false><<<dim3(GT, 4), 512, 0, stream>>>(
      x_vert, whi[0], wlo[0], g1_lin_b, nullptr, nullptr, nullptr, 0.f, nullptr, B1, sums0, N);
  k_gemm5<256, 256, 2, false, false, true, false, true><<<dim3(GT, 4), 512, 0, stream>>>(
      B1, whi[1], wlo[1], nullptr, sums0, g1_n1_g, g1_n1_b, invN, dis, sB, nullptr, N);
  k_agg5<256, false><<<IDIV(N, 4), 256, 0, stream>>>(
      sB, row_ptr, col, dis, g1_c1_b, nullptr, nullptr, nullptr, nullptr, 0.f, sA, N);
  k_colstats_bf<256><<<NB, 256, 0, stream>>>(sA, N, sums1);
  k_gemm5<256, 256, 2, false, false, true, false, true><<<dim3(GT, 4), 512, 0, stream>>>(
      sA, whi[2], wlo[2], nullptr, sums1, g1_n2_g, g1_n2_b, invN, dis, sB, nullptr, N);
  k_agg5<256, true><<<IDIV(N, 4), 256, 0, stream>>>(
      sB, row_ptr, col, dis, g1_c2_b, B1, sums0, g1_n1_g, g1_n1_b, invN, sA, N);

  // ================= block 2 (in 256, hid 128) =================
  k_gemm5<256, 128, 0, false, true, true, true, false><<<dim3(GT, 2), 512, 0, stream>>>(
      sA, whi[3], wlo[3], g2_lin_b, nullptr, nullptr, nullptr, 0.f, nullptr, B2, sums2, N);
  k_gemm5<128, 128, 2, false, false, true, false, true><<<dim3(GT, 2), 512, 0, stream>>>(
      B2, whi[4], wlo[4], nullptr, sums2, g2_n1_g, g2_n1_b, invN, dis, sB, nullptr, N);
  k_agg5<128, false><<<IDIV(N, 4), 256, 0, stream>>>(
      sB, row_ptr, col, dis, g2_c1_b, nullptr, nullptr, nullptr, nullptr, 0.f, sA, N);
  k_colstats_bf<128><<<NB, 256, 0, stream>>>(sA, N, sums3);
  k_gemm5<128, 128, 2, false, false, true, false, true><<<dim3(GT, 2), 512, 0, stream>>>(
      sA, whi[5], wlo[5], nullptr, sums3, g2_n2_g, g2_n2_b, invN, dis, sB, nullptr, N);
  k_agg5<128, true><<<IDIV(N, 4), 256, 0, stream>>>(
      sB, row_ptr, col, dis, g2_c2_b, B2, sums2, g2_n1_g, g2_n1_b, invN, sA, N);

  // ================= head =================
  k_gemm5<128, 128, 0, false, true, true, true, false><<<dim3(GT, 2), 512, 0, stream>>>(
      sA, whi[6], wlo[6], out_b, nullptr, nullptr, nullptr, 0.f, nullptr, sB, sums4, N);
  k_gemm5<128, 64, 2, true, true, true, true, false><<<dim3(GT, 1), 512, 0, stream>>>(
      sB, whi[7], wlo[7], l1_b, sums4, n1_g, n1_b, invN, nullptr, sA, sums5, N);
  k_gemm5<64, 64, 2, true, false, false, true, false><<<dim3(GT, 1), 512, 0, stream>>>(
      sA, whi[8], wlo[8], l2_b, sums5, n2_g, n2_b, invN, nullptr, out, nullptr, N);
}

// Round 12
// 582.884 us; speedup vs baseline: 1.3168x; 1.0729x over previous
//
#include <hip/hip_runtime.h>
#include <cstddef>
#include <cstdint>

#define IDIV(a, b) (((a) + (b) - 1) / (b))

typedef __attribute__((ext_vector_type(8))) short short8;
typedef __attribute__((ext_vector_type(8))) unsigned short ushort8v;
typedef __attribute__((ext_vector_type(4))) float f32x4;

__device__ inline ushort f2bf_rne(float x) {
  uint32_t u = __builtin_bit_cast(uint32_t, x);
  u += 0x7fff + ((u >> 16) & 1);
  return (ushort)(u >> 16);
}
__device__ inline float bf2f(ushort h) {
  uint32_t u = (uint32_t)h << 16;
  return __builtin_bit_cast(float, u);
}

// BN coefficients from raw sums
__device__ inline void bn_coeff(const float* __restrict__ sums, const float* __restrict__ g,
                                const float* __restrict__ bb, float invN, int H, int c,
                                float& sc, float& sh) {
  const float mean = sums[c] * invN;
  float var = sums[H + c] * invN - mean * mean;
  var = var < 0.f ? 0.f : var;
  sc = g[c] * rsqrtf(var + 1e-5f);
  sh = bb[c] - mean * sc;
}

// ---------------------------------------------------------------- utilities

__global__ void k_zero_i32(int* __restrict__ p, int n) {
  int i = blockIdx.x * blockDim.x + threadIdx.x;
  if (i < n) p[i] = 0;
}

__global__ void k_zero_f32(float* __restrict__ p, int n) {
  int i = blockIdx.x * blockDim.x + threadIdx.x;
  if (i < n) p[i] = 0.f;
}

// ---------------------------------------------------------------- CSR build

__global__ void k_count(const int* __restrict__ dst, int E, int* __restrict__ cnt) {
  int i = blockIdx.x * blockDim.x + threadIdx.x;
  if (i < E) atomicAdd(&cnt[dst[i]], 1);
}

__global__ void k_scan_partial(const int* __restrict__ cnt, int n, int* __restrict__ part) {
  __shared__ int sm[256];
  const int t = threadIdx.x;
  const int i = blockIdx.x * 256 + t;
  sm[t] = (i < n) ? cnt[i] : 0;
  __syncthreads();
  for (int off = 128; off > 0; off >>= 1) {
    if (t < off) sm[t] += sm[t + off];
    __syncthreads();
  }
  if (t == 0) part[blockIdx.x] = sm[0];
}

__global__ void k_scan_offsets(int* __restrict__ part, int nb) {
  __shared__ int sm[256];
  const int t = threadIdx.x;
  if (t < nb) sm[t] = part[t];
  __syncthreads();
  if (t == 0) {
    int run = 0;
    for (int i = 0; i < nb; ++i) { int v = sm[i]; sm[i] = run; run += v; }
  }
  __syncthreads();
  if (t < nb) part[t] = sm[t];
}

__global__ void k_scan_final(const int* __restrict__ cnt, int n, const int* __restrict__ part,
                             int* __restrict__ row_ptr) {
  __shared__ int sm[256];
  const int t = threadIdx.x;
  const int i = blockIdx.x * 256 + t;
  const int v = (i < n) ? cnt[i] : 0;
  sm[t] = v;
  __syncthreads();
  for (int off = 1; off < 256; off <<= 1) {
    int x = (t >= off) ? sm[t - off] : 0;
    __syncthreads();
    sm[t] += x;
    __syncthreads();
  }
  if (i < n) row_ptr[i] = part[blockIdx.x] + sm[t] - v;  // exclusive scan
}

__global__ void k_cursor_dis(const int* __restrict__ row_ptr, const int* __restrict__ cnt,
                             int* __restrict__ cursor, float* __restrict__ dis,
                             int* __restrict__ row_ptr_end, int n, int E) {
  int i = blockIdx.x * blockDim.x + threadIdx.x;
  if (i == 0) *row_ptr_end = E;
  if (i < n) {
    cursor[i] = row_ptr[i];
    dis[i] = rsqrtf((float)cnt[i] + 1.0f);
  }
}

__global__ void k_scatter(const int* __restrict__ src, const int* __restrict__ dst, int E,
                          int* __restrict__ cursor, int* __restrict__ col) {
  int i = blockIdx.x * blockDim.x + threadIdx.x;
  if (i < E) {
    int d = dst[i];
    int pos = atomicAdd(&cursor[d], 1);
    col[pos] = src[i];
  }
}

// ---------------------------------------------------------------- weight prep
// W[K][O] fp32 -> Wt_hi[O][K], Wt_lo[O][K] bf16 (transposed + hi/lo split)

struct WSpec { const float* W; ushort* hi; ushort* lo; int K; int O; };
struct WPack { WSpec s[9]; };

__global__ void k_wprep(WPack p) {
  const WSpec w = p.s[blockIdx.y];
  const int total = w.K * w.O;
  for (int i = blockIdx.x * 256 + threadIdx.x; i < total; i += gridDim.x * 256) {
    const int o = i / w.K;
    const int k = i - o * w.K;
    const float v = w.W[(size_t)k * w.O + o];
    const ushort h = f2bf_rne(v);
    w.hi[i] = h;
    w.lo[i] = f2bf_rne(v - bf2f(h));
  }
}

// ---------------------------------------------------------------- unified MFMA GEMM
// C[N,O] = op(A)[N,K] @ W[K,O] (+bias)(*rowscale). BM=256, BN=64, 8 waves.
// W panel staged in LDS ONCE per block -> inner loop is ds_read_b128 + MFMA;
// only streaming A-loads (depth-1 prefetch) touch global.
// WSPLIT: stage+use W-lo plane (2 MFMAs; conv GEMMs use hi-only -> 1 MFMA,
// half the LDS -> double the blocks/CU). PRO: 0 = A bf16; 1 = A fp32->bf16;
// 2 = A bf16 + BN+lrelu (coeff table in LDS). ASPLIT: A hi/lo (+1 MFMA).
// STATS: fused col sum/sumsq (pre-rowscale). RS: scale row by rs[row].

template <int K, int O, int PRO, bool ASPLIT, bool WSPLIT, bool STATS, bool OUTBF, bool BIAS,
          bool RS>
__launch_bounds__(512, 4)
__global__ void k_gemm5(const void* __restrict__ Av, const ushort* __restrict__ Whi,
                        const ushort* __restrict__ Wlo, const float* __restrict__ bias,
                        const float* __restrict__ psums, const float* __restrict__ pg,
                        const float* __restrict__ pbb, float invN,
                        const float* __restrict__ rs, void* __restrict__ Cout,
                        float* __restrict__ sums, int N) {
  constexpr int KS = K / 32;
  constexpr int KP = K + 8;  // padded LDS row (shorts)
  constexpr int MF = 2, NF = 4;
  constexpr int PL = WSPLIT ? 2 : 1;

  const ushort* Ab = (const ushort*)Av;
  const float* Af = (const float*)Av;

  __shared__ ushort Ws[PL][64][KP];
  __shared__ float lcf[(PRO == 2) ? 2 * K : 2];
  __shared__ float sred[STATS ? 8 : 1][NF][16][2];

  const int bm = blockIdx.x * 256;
  const int bo = blockIdx.y * 64;
  const int t = threadIdx.x;
  const int w = t >> 6, l = t & 63;
  const int lr = l & 15;
  const int lk = (l >> 4) * 8;

  if constexpr (PRO == 2) {
    for (int c = t; c < K; c += 512) {
      float sc, sh;
      bn_coeff(psums, pg, pbb, invN, K, c, sc, sh);
      lcf[c] = sc;
      lcf[K + c] = sh;
    }
  }
  // ---- stage W panel into LDS
  {
    constexpr int CPR = K / 8;             // 16B chunks per row
    constexpr int CHUNKS = PL * 64 * CPR;  // total chunks
    for (int i = t; i < CHUNKS; i += 512) {
      const int plane = i / (64 * CPR);
      const int rem = i - plane * 64 * CPR;
      const int row = rem / CPR;
      const int kc = (rem - row * CPR) * 8;
      const ushort* sp = plane ? Wlo : Whi;
      *reinterpret_cast<ushort8v*>(&Ws[plane][row][kc]) =
          *reinterpret_cast<const ushort8v*>(&sp[(size_t)(bo + row) * K + kc]);
    }
  }
  __syncthreads();

  f32x4 acc[MF][NF];
  const f32x4 zero4 = {0.f, 0.f, 0.f, 0.f};
#pragma unroll
  for (int mf = 0; mf < MF; ++mf)
#pragma unroll
    for (int nf = 0; nf < NF; ++nf) acc[mf][nf] = zero4;

  int arow[MF];
#pragma unroll
  for (int mf = 0; mf < MF; ++mf) {
    const int r = bm + w * 32 + mf * 16 + lr;
    arow[mf] = r < N ? r : N - 1;
  }

  short8 ar_[2][MF];
  float4 rawf[2][MF][2];
  short8 ah[MF], al_[MF];

  auto ldA = [&](int ks, int b) {
#pragma unroll
    for (int mf = 0; mf < MF; ++mf) {
      const size_t base = (size_t)arow[mf] * K + ks * 32 + lk;
      if constexpr (PRO == 1) {
        rawf[b][mf][0] = *reinterpret_cast<const float4*>(&Af[base]);
        rawf[b][mf][1] = *reinterpret_cast<const float4*>(&Af[base + 4]);
      } else {
        ar_[b][mf] = *reinterpret_cast<const short8*>(&Ab[base]);
      }
    }
  };
  auto cvtA = [&](int ks, int b) {
    if constexpr (PRO == 0) {
#pragma unroll
      for (int mf = 0; mf < MF; ++mf) ah[mf] = ar_[b][mf];
    } else if constexpr (PRO == 1) {
#pragma unroll
      for (int mf = 0; mf < MF; ++mf) {
        const float f[8] = {rawf[b][mf][0].x, rawf[b][mf][0].y, rawf[b][mf][0].z,
                            rawf[b][mf][0].w, rawf[b][mf][1].x, rawf[b][mf][1].y,
                            rawf[b][mf][1].z, rawf[b][mf][1].w};
        short8 hi;
#pragma unroll
        for (int j = 0; j < 8; ++j) hi[j] = (short)f2bf_rne(f[j]);
        ah[mf] = hi;
      }
    } else {
      const int k0 = ks * 32 + lk;
      const float4 c0v = *reinterpret_cast<const float4*>(&lcf[k0]);
      const float4 c1v = *reinterpret_cast<const float4*>(&lcf[k0 + 4]);
      const float4 h0v = *reinterpret_cast<const float4*>(&lcf[K + k0]);
      const float4 h1v = *reinterpret_cast<const float4*>(&lcf[K + k0 + 4]);
      const float sc[8] = {c0v.x, c0v.y, c0v.z, c0v.w, c1v.x, c1v.y, c1v.z, c1v.w};
      const float sh[8] = {h0v.x, h0v.y, h0v.z, h0v.w, h1v.x, h1v.y, h1v.z, h1v.w};
#pragma unroll
      for (int mf = 0; mf < MF; ++mf) {
        float f[8];
#pragma unroll
        for (int j = 0; j < 8; ++j) {
          float x = bf2f((ushort)ar_[b][mf][j]) * sc[j] + sh[j];
          f[j] = x > 0.f ? x : 0.01f * x;
        }
        short8 hi, lo;
#pragma unroll
        for (int j = 0; j < 8; ++j) {
          const ushort h = f2bf_rne(f[j]);
          hi[j] = (short)h;
          lo[j] = (short)f2bf_rne(f[j] - bf2f(h));
        }
        ah[mf] = hi;
        if (ASPLIT) al_[mf] = lo;
      }
    }
  };

  ldA(0, 0);
#pragma unroll
  for (int ks = 0; ks < KS; ++ks) {
    const int cur = ks & 1;
    if (ks + 1 < KS) ldA(ks + 1, cur ^ 1);
    cvtA(ks, cur);
#pragma unroll
    for (int nf = 0; nf < NF; ++nf) {
      const short8 bhf = *reinterpret_cast<const short8*>(&Ws[0][nf * 16 + lr][ks * 32 + lk]);
#pragma unroll
      for (int mf = 0; mf < MF; ++mf) {
        acc[mf][nf] = __builtin_amdgcn_mfma_f32_16x16x32_bf16(ah[mf], bhf, acc[mf][nf], 0, 0, 0);
        if (ASPLIT)
          acc[mf][nf] = __builtin_amdgcn_mfma_f32_16x16x32_bf16(al_[mf], bhf, acc[mf][nf], 0, 0, 0);
      }
      if (WSPLIT) {
        const short8 blf =
            *reinterpret_cast<const short8*>(&Ws[PL - 1][nf * 16 + lr][ks * 32 + lk]);
#pragma unroll
        for (int mf = 0; mf < MF; ++mf)
          acc[mf][nf] = __builtin_amdgcn_mfma_f32_16x16x32_bf16(ah[mf], blf, acc[mf][nf], 0, 0, 0);
      }
    }
  }

  // ---- epilogue: C[row = bm + w*32 + mf*16 + (l>>4)*4 + rg][col = bo + nf*16 + lr]
  float s[NF], q[NF];
#pragma unroll
  for (int nf = 0; nf < NF; ++nf) { s[nf] = 0.f; q[nf] = 0.f; }
#pragma unroll
  for (int mf = 0; mf < MF; ++mf) {
    const int gr0 = bm + w * 32 + mf * 16 + (l >> 4) * 4;
    float rsv[4];
#pragma unroll
    for (int rg = 0; rg < 4; ++rg) {
      const int row = gr0 + rg;
      rsv[rg] = (RS && row < N) ? rs[row] : 0.f;
    }
#pragma unroll
    for (int nf = 0; nf < NF; ++nf) {
      const int gc = bo + nf * 16 + lr;
      float bval = 0.f;
      if (BIAS) bval = bias[gc];
#pragma unroll
      for (int rg = 0; rg < 4; ++rg) {
        const int row = gr0 + rg;
        if (row < N) {
          float v = acc[mf][nf][rg] + bval;
          if (STATS) { s[nf] += v; q[nf] += v * v; }
          if (RS) v *= rsv[rg];
          if (OUTBF)
            ((ushort*)Cout)[(size_t)row * O + gc] = f2bf_rne(v);
          else
            ((float*)Cout)[(size_t)row * O + gc] = v;
        }
      }
    }
  }

  if (STATS) {
#pragma unroll
    for (int nf = 0; nf < NF; ++nf) {
      s[nf] += __shfl_xor(s[nf], 16);
      s[nf] += __shfl_xor(s[nf], 32);
      q[nf] += __shfl_xor(q[nf], 16);
      q[nf] += __shfl_xor(q[nf], 32);
    }
    if (l < 16) {
#pragma unroll
      for (int nf = 0; nf < NF; ++nf) {
        sred[w][nf][l][0] = s[nf];
        sred[w][nf][l][1] = q[nf];
      }
    }
    __syncthreads();
    if (t < 64) {
      const int nfi = t >> 4;
      const int lri = t & 15;
      float S = 0.f, Q = 0.f;
#pragma unroll
      for (int ww = 0; ww < 8; ++ww) {
        S += sred[ww][nfi][lri][0];
        Q += sred[ww][nfi][lri][1];
      }
      atomicAdd(&sums[bo + t], S);
      atomicAdd(&sums[O + bo + t], Q);
    }
  }
}

// ---------------------------------------------------------------- bf16 column stats

template <int H>
__launch_bounds__(256)
__global__ void k_colstats_bf(const ushort* __restrict__ X, int n, float* __restrict__ sums) {
  constexpr int G = H / 8;
  constexpr int NS = 256 / G;
  const int t = threadIdx.x;
  const int cg = t % G;
  const int sub = t / G;
  const int r0 = blockIdx.x * 256;
  const int rend = (r0 + 256 < n) ? r0 + 256 : n;
  float s[8], q[8];
#pragma unroll
  for (int j = 0; j < 8; ++j) { s[j] = 0.f; q[j] = 0.f; }
  for (int r = r0 + sub; r < rend; r += NS) {
    const ushort8v u = *reinterpret_cast<const ushort8v*>(&X[(size_t)r * H + cg * 8]);
#pragma unroll
    for (int j = 0; j < 8; ++j) {
      const float f = bf2f(u[j]);
      s[j] += f;
      q[j] += f * f;
    }
  }
  __shared__ float red[256][16];
#pragma unroll
  for (int j = 0; j < 8; ++j) { red[t][j] = s[j]; red[t][8 + j] = q[j]; }
  __syncthreads();
  if (sub == 0) {
#pragma unroll
    for (int k = 1; k < NS; ++k) {
      const int u2 = cg + k * G;
#pragma unroll
      for (int j = 0; j < 8; ++j) { s[j] += red[u2][j]; q[j] += red[u2][8 + j]; }
    }
#pragma unroll
    for (int j = 0; j < 8; ++j) {
      atomicAdd(&sums[cg * 8 + j], s[j]);
      atomicAdd(&sums[H + cg * 8 + j], q[j]);
    }
  }
}

// ---------------------------------------------------------------- GCN aggregation
// Hin rows PRE-SCALED by dis:
//   out[d] = (sum_e Hin[col[e]] + Hin[d]) * dis[d] + bias
// 8-deep + 4-deep batched gathers, wave-uniform scalar remainder.
// COMBINE: out = ((x*sc+sh) + r) * 2^-0.5 + x (BN coeffs inline).

template <int H, bool COMBINE>
__launch_bounds__(256)
__global__ void k_agg5(const ushort* __restrict__ Hin, const int* __restrict__ row_ptr,
                       const int* __restrict__ col, const float* __restrict__ dis,
                       const float* __restrict__ bias, const ushort* __restrict__ xin,
                       const float* __restrict__ bnsums, const float* __restrict__ g,
                       const float* __restrict__ bb, float invN,
                       ushort* __restrict__ out, int n) {
  constexpr int V = H / 64;  // 4 or 2
  const int lane = threadIdx.x & 63;
  const int node = blockIdx.x * 4 + (threadIdx.x >> 6);
  if (node >= n) return;
  const int lv = lane * V;
  const int beg = row_ptr[node];
  const int end = row_ptr[node + 1];

  float acc[V];
#pragma unroll
  for (int j = 0; j < V; ++j) acc[j] = 0.f;

  auto add1 = [&](int sidx) {
    if constexpr (V == 4) {
      const ushort4 u = *reinterpret_cast<const ushort4*>(&Hin[(size_t)sidx * H + lv]);
      acc[0] += bf2f(u.x); acc[1] += bf2f(u.y);
      acc[2] += bf2f(u.z); acc[3] += bf2f(u.w);
    } else {
      const ushort2 u = *reinterpret_cast<const ushort2*>(&Hin[(size_t)sidx * H + lv]);
      acc[0] += bf2f(u.x); acc[1] += bf2f(u.y);
    }
  };

  int e = beg;
  for (; e + 8 <= end; e += 8) {
    int s8[8];
#pragma unroll
    for (int i = 0; i < 8; ++i) s8[i] = col[e + i];
    if constexpr (V == 4) {
      ushort4 u[8];
#pragma unroll
      for (int i = 0; i < 8; ++i)
        u[i] = *reinterpret_cast<const ushort4*>(&Hin[(size_t)s8[i] * H + lv]);
#pragma unroll
      for (int i = 0; i < 8; ++i) {
        acc[0] += bf2f(u[i].x); acc[1] += bf2f(u[i].y);
        acc[2] += bf2f(u[i].z); acc[3] += bf2f(u[i].w);
      }
    } else {
      ushort2 u[8];
#pragma unroll
      for (int i = 0; i < 8; ++i)
        u[i] = *reinterpret_cast<const ushort2*>(&Hin[(size_t)s8[i] * H + lv]);
#pragma unroll
      for (int i = 0; i < 8; ++i) {
        acc[0] += bf2f(u[i].x); acc[1] += bf2f(u[i].y);
      }
    }
  }
  if (e + 4 <= end) {
    int s4[4];
#pragma unroll
    for (int i = 0; i < 4; ++i) s4[i] = col[e + i];
    if constexpr (V == 4) {
      ushort4 u[4];
#pragma unroll
      for (int i = 0; i < 4; ++i)
        u[i] = *reinterpret_cast<const ushort4*>(&Hin[(size_t)s4[i] * H + lv]);
#pragma unroll
      for (int i = 0; i < 4; ++i) {
        acc[0] += bf2f(u[i].x); acc[1] += bf2f(u[i].y);
        acc[2] += bf2f(u[i].z); acc[3] += bf2f(u[i].w);
      }
    } else {
      ushort2 u[4];
#pragma unroll
      for (int i = 0; i < 4; ++i)
        u[i] = *reinterpret_cast<const ushort2*>(&Hin[(size_t)s4[i] * H + lv]);
#pragma unroll
      for (int i = 0; i < 4; ++i) {
        acc[0] += bf2f(u[i].x); acc[1] += bf2f(u[i].y);
      }
    }
    e += 4;
  }
  for (; e <= end; ++e) add1((e == end) ? node : col[e]);  // remainder + self

  const float dd = dis[node];
  float r[V];
#pragma unroll
  for (int j = 0; j < V; ++j) r[j] = acc[j] * dd + bias[lv + j];

  if (COMBINE) {
    const float cinv = 0.70710678118654752f;
    const ushort* xp = &xin[(size_t)node * H + lv];
#pragma unroll
    for (int j = 0; j < V; ++j) {
      const float x = bf2f(xp[j]);
      float sc, sh;
      bn_coeff(bnsums, g, bb, invN, H, lv + j, sc, sh);
      r[j] = (x * sc + sh + r[j]) * cinv + x;
    }
  }

  if constexpr (V == 4) {
    ushort4 o;
    o.x = f2bf_rne(r[0]); o.y = f2bf_rne(r[1]);
    o.z = f2bf_rne(r[2]); o.w = f2bf_rne(r[3]);
    *reinterpret_cast<ushort4*>(&out[(size_t)node * H + lv]) = o;
  } else {
    ushort2 o;
    o.x = f2bf_rne(r[0]); o.y = f2bf_rne(r[1]);
    *reinterpret_cast<ushort2*>(&out[(size_t)node * H + lv]) = o;
  }
}

// ---------------------------------------------------------------- launch

extern "C" void kernel_launch(void* const* d_in, const int* in_sizes, int n_in,
                              void* d_out, int out_size, void* d_ws, size_t ws_size,
                              hipStream_t stream) {
  const int N = in_sizes[0] / 128;
  const int E = in_sizes[1] / 2;

  const float* x_vert = (const float*)d_in[0];
  const int* src = (const int*)d_in[1];
  const int* dst = src + E;
  const float* g1_lin_W = (const float*)d_in[2];
  const float* g1_lin_b = (const float*)d_in[3];
  const float* g1_c1_W = (const float*)d_in[4];
  const float* g1_c1_b = (const float*)d_in[5];
  const float* g1_c2_W = (const float*)d_in[6];
  const float* g1_c2_b = (const float*)d_in[7];
  const float* g1_n1_g = (const float*)d_in[8];
  const float* g1_n1_b = (const float*)d_in[9];
  const float* g1_n2_g = (const float*)d_in[10];
  const float* g1_n2_b = (const float*)d_in[11];
  const float* g2_lin_W = (const float*)d_in[12];
  const float* g2_lin_b = (const float*)d_in[13];
  const float* g2_c1_W = (const float*)d_in[14];
  const float* g2_c1_b = (const float*)d_in[15];
  const float* g2_c2_W = (const float*)d_in[16];
  const float* g2_c2_b = (const float*)d_in[17];
  const float* g2_n1_g = (const float*)d_in[18];
  const float* g2_n1_b = (const float*)d_in[19];
  const float* g2_n2_g = (const float*)d_in[20];
  const float* g2_n2_b = (const float*)d_in[21];
  const float* out_W = (const float*)d_in[22];
  const float* out_b = (const float*)d_in[23];
  const float* n1_g = (const float*)d_in[24];
  const float* n1_b = (const float*)d_in[25];
  const float* l1_W = (const float*)d_in[26];
  const float* l1_b = (const float*)d_in[27];
  const float* n2_g = (const float*)d_in[28];
  const float* n2_b = (const float*)d_in[29];
  const float* l2_W = (const float*)d_in[30];
  const float* l2_b = (const float*)d_in[31];

  float* out = (float*)d_out;

  // ---- workspace carve-up
  size_t off = 0;
  auto alloc = [&](size_t bytes) -> void* {
    void* p = (char*)d_ws + off;
    off += (bytes + 255) & ~(size_t)255;
    return p;
  };
  ushort* B1 = (ushort*)alloc((size_t)N * 256 * 2);  // x_in block1 (bf16 residual src)
  ushort* B2 = (ushort*)alloc((size_t)N * 128 * 2);  // x_in block2 (bf16 residual src)
  ushort* sA = (ushort*)alloc((size_t)N * 256 * 2);  // rotating bf16 slot A
  ushort* sB = (ushort*)alloc((size_t)N * 256 * 2);  // rotating bf16 slot B
  int* cnt = (int*)alloc((size_t)N * 4);
  int* row_ptr = (int*)alloc((size_t)(N + 1) * 4);
  int* cursor = (int*)alloc((size_t)N * 4);
  int* col = (int*)alloc((size_t)E * 4);
  int* part = (int*)alloc(1024 * 4);
  float* dis = (float*)alloc((size_t)N * 4);
  float* sums = (float*)alloc(6 * 512 * 4);

  const int wk[9] = {128, 256, 256, 256, 128, 128, 128, 128, 64};
  const int wo[9] = {256, 256, 256, 128, 128, 128, 128, 64, 64};
  const float* wsrc[9] = {g1_lin_W, g1_c1_W, g1_c2_W, g2_lin_W, g2_c1_W,
                          g2_c2_W, out_W, l1_W, l2_W};
  ushort* whi[9];
  ushort* wlo[9];
  for (int i = 0; i < 9; ++i) {
    whi[i] = (ushort*)alloc((size_t)wk[i] * wo[i] * 2);
    wlo[i] = (ushort*)alloc((size_t)wk[i] * wo[i] * 2);
  }
  (void)ws_size;
  (void)n_in;
  (void)out_size;

  const int NB = IDIV(N, 256);
  const int GT = IDIV(N, 256);  // BM=256 grid x
  const float invN = 1.0f / (float)N;
  float* sums0 = sums + 0 * 512;
  float* sums1 = sums + 1 * 512;
  float* sums2 = sums + 2 * 512;
  float* sums3 = sums + 3 * 512;
  float* sums4 = sums + 4 * 512;
  float* sums5 = sums + 5 * 512;

  // ---- CSR build + weight prep
  k_zero_i32<<<NB, 256, 0, stream>>>(cnt, N);
  k_zero_f32<<<IDIV(6 * 512, 256), 256, 0, stream>>>(sums, 6 * 512);
  {
    WPack p;
    for (int i = 0; i < 9; ++i) p.s[i] = WSpec{wsrc[i], whi[i], wlo[i], wk[i], wo[i]};
    k_wprep<<<dim3(64, 9), 256, 0, stream>>>(p);
  }
  k_count<<<IDIV(E, 256), 256, 0, stream>>>(dst, E, cnt);
  k_scan_partial<<<NB, 256, 0, stream>>>(cnt, N, part);
  k_scan_offsets<<<1, 256, 0, stream>>>(part, NB);
  k_scan_final<<<NB, 256, 0, stream>>>(cnt, N, part, row_ptr);
  k_cursor_dis<<<NB, 256, 0, stream>>>(row_ptr, cnt, cursor, dis, row_ptr + N, N, E);
  k_scatter<<<IDIV(E, 256), 256, 0, stream>>>(src, dst, E, cursor, col);

  // ================= block 1 (in 128, hid 256) =================
  k_gemm5<128, 256, 1, false, true, true, true, true, false><<<dim3(GT, 4), 512, 0, stream>>>(
      x_vert, whi[0], wlo[0], g1_lin_b, nullptr, nullptr, nullptr, 0.f, nullptr, B1, sums0, N);
  k_gemm5<256, 256, 2, false, false, false, true, false, true><<<dim3(GT, 4), 512, 0, stream>>>(
      B1, whi[1], wlo[1], nullptr, sums0, g1_n1_g, g1_n1_b, invN, dis, sB, nullptr, N);
  k_agg5<256, false><<<IDIV(N, 4), 256, 0, stream>>>(
      sB, row_ptr, col, dis, g1_c1_b, nullptr, nullptr, nullptr, nullptr, 0.f, sA, N);
  k_colstats_bf<256><<<NB, 256, 0, stream>>>(sA, N, sums1);
  k_gemm5<256, 256, 2, false, false, false, true, false, true><<<dim3(GT, 4), 512, 0, stream>>>(
      sA, whi[2], wlo[2], nullptr, sums1, g1_n2_g, g1_n2_b, invN, dis, sB, nullptr, N);
  k_agg5<256, true><<<IDIV(N, 4), 256, 0, stream>>>(
      sB, row_ptr, col, dis, g1_c2_b, B1, sums0, g1_n1_g, g1_n1_b, invN, sA, N);

  // ================= block 2 (in 256, hid 128) =================
  k_gemm5<256, 128, 0, false, true, true, true, true, false><<<dim3(GT, 2), 512, 0, stream>>>(
      sA, whi[3], wlo[3], g2_lin_b, nullptr, nullptr, nullptr, 0.f, nullptr, B2, sums2, N);
  k_gemm5<128, 128, 2, false, false, false, true, false, true><<<dim3(GT, 2), 512, 0, stream>>>(
      B2, whi[4], wlo[4], nullptr, sums2, g2_n1_g, g2_n1_b, invN, dis, sB, nullptr, N);
  k_agg5<128, false><<<IDIV(N, 4), 256, 0, stream>>>(
      sB, row_ptr, col, dis, g2_c1_b, nullptr, nullptr, nullptr, nullptr, 0.f, sA, N);
  k_colstats_bf<128><<<NB, 256, 0, stream>>>(sA, N, sums3);
  k_gemm5<128, 128, 2, false, false, false, true, false, true><<<dim3(GT, 2), 512, 0, stream>>>(
      sA, whi[5], wlo[5], nullptr, sums3, g2_n2_g, g2_n2_b, invN, dis, sB, nullptr, N);
  k_agg5<128, true><<<IDIV(N, 4), 256, 0, stream>>>(
      sB, row_ptr, col, dis, g2_c2_b, B2, sums2, g2_n1_g, g2_n1_b, invN, sA, N);

  // ================= head =================
  k_gemm5<128, 128, 0, false, true, true, true, true, false><<<dim3(GT, 2), 512, 0, stream>>>(
      sA, whi[6], wlo[6], out_b, nullptr, nullptr, nullptr, 0.f, nullptr, sB, sums4, N);
  k_gemm5<128, 64, 2, true, true, true, true, true, false><<<dim3(GT, 1), 512, 0, stream>>>(
      sB, whi[7], wlo[7], l1_b, sums4, n1_g, n1_b, invN, nullptr, sA, sums5, N);
  k_gemm5<64, 64, 2, true, true, false, false, true, false><<<dim3(GT, 1), 512, 0, stream>>>(
      sA, whi[8], wlo[8], l2_b, sums5, n2_g, n2_b, invN, nullptr, out, nullptr, N);
}

// Round 13
// 580.814 us; speedup vs baseline: 1.3215x; 1.0036x over previous
//
#include <hip/hip_runtime.h>
#include <cstddef>
#include <cstdint>

#define IDIV(a, b) (((a) + (b) - 1) / (b))

typedef __attribute__((ext_vector_type(8))) short short8;
typedef __attribute__((ext_vector_type(8))) unsigned short ushort8v;
typedef __attribute__((ext_vector_type(4))) float f32x4;

__device__ inline ushort f2bf_rne(float x) {
  uint32_t u = __builtin_bit_cast(uint32_t, x);
  u += 0x7fff + ((u >> 16) & 1);
  return (ushort)(u >> 16);
}
__device__ inline float bf2f(ushort h) {
  uint32_t u = (uint32_t)h << 16;
  return __builtin_bit_cast(float, u);
}

// BN coefficients from raw sums
__device__ inline void bn_coeff(const float* __restrict__ sums, const float* __restrict__ g,
                                const float* __restrict__ bb, float invN, int H, int c,
                                float& sc, float& sh) {
  const float mean = sums[c] * invN;
  float var = sums[H + c] * invN - mean * mean;
  var = var < 0.f ? 0.f : var;
  sc = g[c] * rsqrtf(var + 1e-5f);
  sh = bb[c] - mean * sc;
}

// ---------------------------------------------------------------- utilities

__global__ void k_zero_i32(int* __restrict__ p, int n) {
  int i = blockIdx.x * blockDim.x + threadIdx.x;
  if (i < n) p[i] = 0;
}

__global__ void k_zero_f32(float* __restrict__ p, int n) {
  int i = blockIdx.x * blockDim.x + threadIdx.x;
  if (i < n) p[i] = 0.f;
}

// ---------------------------------------------------------------- CSR build

__global__ void k_count(const int* __restrict__ dst, int E, int* __restrict__ cnt) {
  int i = blockIdx.x * blockDim.x + threadIdx.x;
  if (i < E) atomicAdd(&cnt[dst[i]], 1);
}

__global__ void k_scan_partial(const int* __restrict__ cnt, int n, int* __restrict__ part) {
  __shared__ int sm[256];
  const int t = threadIdx.x;
  const int i = blockIdx.x * 256 + t;
  sm[t] = (i < n) ? cnt[i] : 0;
  __syncthreads();
  for (int off = 128; off > 0; off >>= 1) {
    if (t < off) sm[t] += sm[t + off];
    __syncthreads();
  }
  if (t == 0) part[blockIdx.x] = sm[0];
}

__global__ void k_scan_offsets(int* __restrict__ part, int nb) {
  __shared__ int sm[256];
  const int t = threadIdx.x;
  if (t < nb) sm[t] = part[t];
  __syncthreads();
  if (t == 0) {
    int run = 0;
    for (int i = 0; i < nb; ++i) { int v = sm[i]; sm[i] = run; run += v; }
  }
  __syncthreads();
  if (t < nb) part[t] = sm[t];
}

__global__ void k_scan_final(const int* __restrict__ cnt, int n, const int* __restrict__ part,
                             int* __restrict__ row_ptr) {
  __shared__ int sm[256];
  const int t = threadIdx.x;
  const int i = blockIdx.x * 256 + t;
  const int v = (i < n) ? cnt[i] : 0;
  sm[t] = v;
  __syncthreads();
  for (int off = 1; off < 256; off <<= 1) {
    int x = (t >= off) ? sm[t - off] : 0;
    __syncthreads();
    sm[t] += x;
    __syncthreads();
  }
  if (i < n) row_ptr[i] = part[blockIdx.x] + sm[t] - v;  // exclusive scan
}

__global__ void k_cursor_dis(const int* __restrict__ row_ptr, const int* __restrict__ cnt,
                             int* __restrict__ cursor, float* __restrict__ dis,
                             int* __restrict__ row_ptr_end, int n, int E) {
  int i = blockIdx.x * blockDim.x + threadIdx.x;
  if (i == 0) *row_ptr_end = E;
  if (i < n) {
    cursor[i] = row_ptr[i];
    dis[i] = rsqrtf((float)cnt[i] + 1.0f);
  }
}

__global__ void k_scatter(const int* __restrict__ src, const int* __restrict__ dst, int E,
                          int* __restrict__ cursor, int* __restrict__ col) {
  int i = blockIdx.x * blockDim.x + threadIdx.x;
  if (i < E) {
    int d = dst[i];
    int pos = atomicAdd(&cursor[d], 1);
    col[pos] = src[i];
  }
}

// ---------------------------------------------------------------- weight prep
// W[K][O] fp32 -> Wt_hi[O][K], Wt_lo[O][K] bf16 (transposed + hi/lo split)

struct WSpec { const float* W; ushort* hi; ushort* lo; int K; int O; };
struct WPack { WSpec s[9]; };

__global__ void k_wprep(WPack p) {
  const WSpec w = p.s[blockIdx.y];
  const int total = w.K * w.O;
  for (int i = blockIdx.x * 256 + threadIdx.x; i < total; i += gridDim.x * 256) {
    const int o = i / w.K;
    const int k = i - o * w.K;
    const float v = w.W[(size_t)k * w.O + o];
    const ushort h = f2bf_rne(v);
    w.hi[i] = h;
    w.lo[i] = f2bf_rne(v - bf2f(h));
  }
}

// ---------------------------------------------------------------- unified MFMA GEMM
// C[N,O] = op(A)[N,K] @ W[K,O] (+bias)(*rowscale). BM=256, BN=64, 8 waves.
// W panel staged in LDS ONCE per block -> inner loop is ds_read_b128 + MFMA;
// only streaming A-loads (DEPTH-2 prefetch, 3-slot rotation, fully unrolled
// so all buffer indices are compile-time) touch global.
// WSPLIT: stage+use W-lo plane (2 MFMAs; conv GEMMs hi-only -> 1 MFMA,
// half the LDS). PRO: 0 = A bf16; 1 = A fp32->bf16; 2 = A bf16 + BN+lrelu
// (coeff table in LDS). ASPLIT: A hi/lo (+1 MFMA). STATS: fused col
// sum/sumsq (pre-rowscale). RS: scale row by rs[row].

template <int K, int O, int PRO, bool ASPLIT, bool WSPLIT, bool STATS, bool OUTBF, bool BIAS,
          bool RS>
__launch_bounds__(512, 4)
__global__ void k_gemm5(const void* __restrict__ Av, const ushort* __restrict__ Whi,
                        const ushort* __restrict__ Wlo, const float* __restrict__ bias,
                        const float* __restrict__ psums, const float* __restrict__ pg,
                        const float* __restrict__ pbb, float invN,
                        const float* __restrict__ rs, void* __restrict__ Cout,
                        float* __restrict__ sums, int N) {
  constexpr int KS = K / 32;
  constexpr int KP = K + 8;  // padded LDS row (shorts)
  constexpr int MF = 2, NF = 4;
  constexpr int PL = WSPLIT ? 2 : 1;
  constexpr int NB_ = (KS < 3) ? KS : 3;  // A prefetch slots (depth-2)

  const ushort* Ab = (const ushort*)Av;
  const float* Af = (const float*)Av;

  __shared__ ushort Ws[PL][64][KP];
  __shared__ float lcf[(PRO == 2) ? 2 * K : 2];
  __shared__ float sred[STATS ? 8 : 1][NF][16][2];

  const int bm = blockIdx.x * 256;
  const int bo = blockIdx.y * 64;
  const int t = threadIdx.x;
  const int w = t >> 6, l = t & 63;
  const int lr = l & 15;
  const int lk = (l >> 4) * 8;

  if constexpr (PRO == 2) {
    for (int c = t; c < K; c += 512) {
      float sc, sh;
      bn_coeff(psums, pg, pbb, invN, K, c, sc, sh);
      lcf[c] = sc;
      lcf[K + c] = sh;
    }
  }
  // ---- stage W panel into LDS
  {
    constexpr int CPR = K / 8;             // 16B chunks per row
    constexpr int CHUNKS = PL * 64 * CPR;  // total chunks
    for (int i = t; i < CHUNKS; i += 512) {
      const int plane = i / (64 * CPR);
      const int rem = i - plane * 64 * CPR;
      const int row = rem / CPR;
      const int kc = (rem - row * CPR) * 8;
      const ushort* sp = plane ? Wlo : Whi;
      *reinterpret_cast<ushort8v*>(&Ws[plane][row][kc]) =
          *reinterpret_cast<const ushort8v*>(&sp[(size_t)(bo + row) * K + kc]);
    }
  }
  __syncthreads();

  f32x4 acc[MF][NF];
  const f32x4 zero4 = {0.f, 0.f, 0.f, 0.f};
#pragma unroll
  for (int mf = 0; mf < MF; ++mf)
#pragma unroll
    for (int nf = 0; nf < NF; ++nf) acc[mf][nf] = zero4;

  int arow[MF];
#pragma unroll
  for (int mf = 0; mf < MF; ++mf) {
    const int r = bm + w * 32 + mf * 16 + lr;
    arow[mf] = r < N ? r : N - 1;
  }

  short8 ar_[NB_][MF];
  float4 rawf[NB_][MF][2];
  short8 ah[MF], al_[MF];

  auto ldA = [&](int ks, int b) {
#pragma unroll
    for (int mf = 0; mf < MF; ++mf) {
      const size_t base = (size_t)arow[mf] * K + ks * 32 + lk;
      if constexpr (PRO == 1) {
        rawf[b][mf][0] = *reinterpret_cast<const float4*>(&Af[base]);
        rawf[b][mf][1] = *reinterpret_cast<const float4*>(&Af[base + 4]);
      } else {
        ar_[b][mf] = *reinterpret_cast<const short8*>(&Ab[base]);
      }
    }
  };
  auto cvtA = [&](int ks, int b) {
    if constexpr (PRO == 0) {
#pragma unroll
      for (int mf = 0; mf < MF; ++mf) ah[mf] = ar_[b][mf];
    } else if constexpr (PRO == 1) {
#pragma unroll
      for (int mf = 0; mf < MF; ++mf) {
        const float f[8] = {rawf[b][mf][0].x, rawf[b][mf][0].y, rawf[b][mf][0].z,
                            rawf[b][mf][0].w, rawf[b][mf][1].x, rawf[b][mf][1].y,
                            rawf[b][mf][1].z, rawf[b][mf][1].w};
        short8 hi;
#pragma unroll
        for (int j = 0; j < 8; ++j) hi[j] = (short)f2bf_rne(f[j]);
        ah[mf] = hi;
      }
    } else {
      const int k0 = ks * 32 + lk;
      const float4 c0v = *reinterpret_cast<const float4*>(&lcf[k0]);
      const float4 c1v = *reinterpret_cast<const float4*>(&lcf[k0 + 4]);
      const float4 h0v = *reinterpret_cast<const float4*>(&lcf[K + k0]);
      const float4 h1v = *reinterpret_cast<const float4*>(&lcf[K + k0 + 4]);
      const float sc[8] = {c0v.x, c0v.y, c0v.z, c0v.w, c1v.x, c1v.y, c1v.z, c1v.w};
      const float sh[8] = {h0v.x, h0v.y, h0v.z, h0v.w, h1v.x, h1v.y, h1v.z, h1v.w};
#pragma unroll
      for (int mf = 0; mf < MF; ++mf) {
        float f[8];
#pragma unroll
        for (int j = 0; j < 8; ++j) {
          float x = bf2f((ushort)ar_[b][mf][j]) * sc[j] + sh[j];
          f[j] = x > 0.f ? x : 0.01f * x;
        }
        short8 hi, lo;
#pragma unroll
        for (int j = 0; j < 8; ++j) {
          const ushort h = f2bf_rne(f[j]);
          hi[j] = (short)h;
          lo[j] = (short)f2bf_rne(f[j] - bf2f(h));
        }
        ah[mf] = hi;
        if (ASPLIT) al_[mf] = lo;
      }
    }
  };

  // depth-2 prefetch prologue
  ldA(0, 0);
  if (KS > 1) ldA(1, 1 % NB_);
#pragma unroll
  for (int ks = 0; ks < KS; ++ks) {
    const int cur = ks % NB_;
    if (ks + 2 < KS) ldA(ks + 2, (ks + 2) % NB_);
    cvtA(ks, cur);
#pragma unroll
    for (int nf = 0; nf < NF; ++nf) {
      const short8 bhf = *reinterpret_cast<const short8*>(&Ws[0][nf * 16 + lr][ks * 32 + lk]);
#pragma unroll
      for (int mf = 0; mf < MF; ++mf) {
        acc[mf][nf] = __builtin_amdgcn_mfma_f32_16x16x32_bf16(ah[mf], bhf, acc[mf][nf], 0, 0, 0);
        if (ASPLIT)
          acc[mf][nf] = __builtin_amdgcn_mfma_f32_16x16x32_bf16(al_[mf], bhf, acc[mf][nf], 0, 0, 0);
      }
      if (WSPLIT) {
        const short8 blf =
            *reinterpret_cast<const short8*>(&Ws[PL - 1][nf * 16 + lr][ks * 32 + lk]);
#pragma unroll
        for (int mf = 0; mf < MF; ++mf)
          acc[mf][nf] = __builtin_amdgcn_mfma_f32_16x16x32_bf16(ah[mf], blf, acc[mf][nf], 0, 0, 0);
      }
    }
  }

  // ---- epilogue: C[row = bm + w*32 + mf*16 + (l>>4)*4 + rg][col = bo + nf*16 + lr]
  float s[NF], q[NF];
#pragma unroll
  for (int nf = 0; nf < NF; ++nf) { s[nf] = 0.f; q[nf] = 0.f; }
#pragma unroll
  for (int mf = 0; mf < MF; ++mf) {
    const int gr0 = bm + w * 32 + mf * 16 + (l >> 4) * 4;
    float rsv[4];
#pragma unroll
    for (int rg = 0; rg < 4; ++rg) {
      const int row = gr0 + rg;
      rsv[rg] = (RS && row < N) ? rs[row] : 0.f;
    }
#pragma unroll
    for (int nf = 0; nf < NF; ++nf) {
      const int gc = bo + nf * 16 + lr;
      float bval = 0.f;
      if (BIAS) bval = bias[gc];
#pragma unroll
      for (int rg = 0; rg < 4; ++rg) {
        const int row = gr0 + rg;
        if (row < N) {
          float v = acc[mf][nf][rg] + bval;
          if (STATS) { s[nf] += v; q[nf] += v * v; }
          if (RS) v *= rsv[rg];
          if (OUTBF)
            ((ushort*)Cout)[(size_t)row * O + gc] = f2bf_rne(v);
          else
            ((float*)Cout)[(size_t)row * O + gc] = v;
        }
      }
    }
  }

  if (STATS) {
#pragma unroll
    for (int nf = 0; nf < NF; ++nf) {
      s[nf] += __shfl_xor(s[nf], 16);
      s[nf] += __shfl_xor(s[nf], 32);
      q[nf] += __shfl_xor(q[nf], 16);
      q[nf] += __shfl_xor(q[nf], 32);
    }
    if (l < 16) {
#pragma unroll
      for (int nf = 0; nf < NF; ++nf) {
        sred[w][nf][l][0] = s[nf];
        sred[w][nf][l][1] = q[nf];
      }
    }
    __syncthreads();
    if (t < 64) {
      const int nfi = t >> 4;
      const int lri = t & 15;
      float S = 0.f, Q = 0.f;
#pragma unroll
      for (int ww = 0; ww < 8; ++ww) {
        S += sred[ww][nfi][lri][0];
        Q += sred[ww][nfi][lri][1];
      }
      atomicAdd(&sums[bo + t], S);
      atomicAdd(&sums[O + bo + t], Q);
    }
  }
}

// ---------------------------------------------------------------- bf16 column stats

template <int H>
__launch_bounds__(256)
__global__ void k_colstats_bf(const ushort* __restrict__ X, int n, float* __restrict__ sums) {
  constexpr int G = H / 8;
  constexpr int NS = 256 / G;
  const int t = threadIdx.x;
  const int cg = t % G;
  const int sub = t / G;
  const int r0 = blockIdx.x * 256;
  const int rend = (r0 + 256 < n) ? r0 + 256 : n;
  float s[8], q[8];
#pragma unroll
  for (int j = 0; j < 8; ++j) { s[j] = 0.f; q[j] = 0.f; }
  for (int r = r0 + sub; r < rend; r += NS) {
    const ushort8v u = *reinterpret_cast<const ushort8v*>(&X[(size_t)r * H + cg * 8]);
#pragma unroll
    for (int j = 0; j < 8; ++j) {
      const float f = bf2f(u[j]);
      s[j] += f;
      q[j] += f * f;
    }
  }
  __shared__ float red[256][16];
#pragma unroll
  for (int j = 0; j < 8; ++j) { red[t][j] = s[j]; red[t][8 + j] = q[j]; }
  __syncthreads();
  if (sub == 0) {
#pragma unroll
    for (int k = 1; k < NS; ++k) {
      const int u2 = cg + k * G;
#pragma unroll
      for (int j = 0; j < 8; ++j) { s[j] += red[u2][j]; q[j] += red[u2][8 + j]; }
    }
#pragma unroll
    for (int j = 0; j < 8; ++j) {
      atomicAdd(&sums[cg * 8 + j], s[j]);
      atomicAdd(&sums[H + cg * 8 + j], q[j]);
    }
  }
}

// ---------------------------------------------------------------- GCN aggregation
// Hin rows PRE-SCALED by dis:
//   out[d] = (sum_e Hin[col[e]] + Hin[d]) * dis[d] + bias
// 8-deep + 4-deep batched gathers, wave-uniform scalar remainder.
// COMBINE: out = ((x*sc+sh) + r) * 2^-0.5 + x (BN coeffs inline).

template <int H, bool COMBINE>
__launch_bounds__(256)
__global__ void k_agg5(const ushort* __restrict__ Hin, const int* __restrict__ row_ptr,
                       const int* __restrict__ col, const float* __restrict__ dis,
                       const float* __restrict__ bias, const ushort* __restrict__ xin,
                       const float* __restrict__ bnsums, const float* __restrict__ g,
                       const float* __restrict__ bb, float invN,
                       ushort* __restrict__ out, int n) {
  constexpr int V = H / 64;  // 4 or 2
  const int lane = threadIdx.x & 63;
  const int node = blockIdx.x * 4 + (threadIdx.x >> 6);
  if (node >= n) return;
  const int lv = lane * V;
  const int beg = row_ptr[node];
  const int end = row_ptr[node + 1];

  float acc[V];
#pragma unroll
  for (int j = 0; j < V; ++j) acc[j] = 0.f;

  auto add1 = [&](int sidx) {
    if constexpr (V == 4) {
      const ushort4 u = *reinterpret_cast<const ushort4*>(&Hin[(size_t)sidx * H + lv]);
      acc[0] += bf2f(u.x); acc[1] += bf2f(u.y);
      acc[2] += bf2f(u.z); acc[3] += bf2f(u.w);
    } else {
      const ushort2 u = *reinterpret_cast<const ushort2*>(&Hin[(size_t)sidx * H + lv]);
      acc[0] += bf2f(u.x); acc[1] += bf2f(u.y);
    }
  };

  int e = beg;
  for (; e + 8 <= end; e += 8) {
    int s8[8];
#pragma unroll
    for (int i = 0; i < 8; ++i) s8[i] = col[e + i];
    if constexpr (V == 4) {
      ushort4 u[8];
#pragma unroll
      for (int i = 0; i < 8; ++i)
        u[i] = *reinterpret_cast<const ushort4*>(&Hin[(size_t)s8[i] * H + lv]);
#pragma unroll
      for (int i = 0; i < 8; ++i) {
        acc[0] += bf2f(u[i].x); acc[1] += bf2f(u[i].y);
        acc[2] += bf2f(u[i].z); acc[3] += bf2f(u[i].w);
      }
    } else {
      ushort2 u[8];
#pragma unroll
      for (int i = 0; i < 8; ++i)
        u[i] = *reinterpret_cast<const ushort2*>(&Hin[(size_t)s8[i] * H + lv]);
#pragma unroll
      for (int i = 0; i < 8; ++i) {
        acc[0] += bf2f(u[i].x); acc[1] += bf2f(u[i].y);
      }
    }
  }
  if (e + 4 <= end) {
    int s4[4];
#pragma unroll
    for (int i = 0; i < 4; ++i) s4[i] = col[e + i];
    if constexpr (V == 4) {
      ushort4 u[4];
#pragma unroll
      for (int i = 0; i < 4; ++i)
        u[i] = *reinterpret_cast<const ushort4*>(&Hin[(size_t)s4[i] * H + lv]);
#pragma unroll
      for (int i = 0; i < 4; ++i) {
        acc[0] += bf2f(u[i].x); acc[1] += bf2f(u[i].y);
        acc[2] += bf2f(u[i].z); acc[3] += bf2f(u[i].w);
      }
    } else {
      ushort2 u[4];
#pragma unroll
      for (int i = 0; i < 4; ++i)
        u[i] = *reinterpret_cast<const ushort2*>(&Hin[(size_t)s4[i] * H + lv]);
#pragma unroll
      for (int i = 0; i < 4; ++i) {
        acc[0] += bf2f(u[i].x); acc[1] += bf2f(u[i].y);
      }
    }
    e += 4;
  }
  for (; e <= end; ++e) add1((e == end) ? node : col[e]);  // remainder + self

  const float dd = dis[node];
  float r[V];
#pragma unroll
  for (int j = 0; j < V; ++j) r[j] = acc[j] * dd + bias[lv + j];

  if (COMBINE) {
    const float cinv = 0.70710678118654752f;
    const ushort* xp = &xin[(size_t)node * H + lv];
#pragma unroll
    for (int j = 0; j < V; ++j) {
      const float x = bf2f(xp[j]);
      float sc, sh;
      bn_coeff(bnsums, g, bb, invN, H, lv + j, sc, sh);
      r[j] = (x * sc + sh + r[j]) * cinv + x;
    }
  }

  if constexpr (V == 4) {
    ushort4 o;
    o.x = f2bf_rne(r[0]); o.y = f2bf_rne(r[1]);
    o.z = f2bf_rne(r[2]); o.w = f2bf_rne(r[3]);
    *reinterpret_cast<ushort4*>(&out[(size_t)node * H + lv]) = o;
  } else {
    ushort2 o;
    o.x = f2bf_rne(r[0]); o.y = f2bf_rne(r[1]);
    *reinterpret_cast<ushort2*>(&out[(size_t)node * H + lv]) = o;
  }
}

// ---------------------------------------------------------------- launch

extern "C" void kernel_launch(void* const* d_in, const int* in_sizes, int n_in,
                              void* d_out, int out_size, void* d_ws, size_t ws_size,
                              hipStream_t stream) {
  const int N = in_sizes[0] / 128;
  const int E = in_sizes[1] / 2;

  const float* x_vert = (const float*)d_in[0];
  const int* src = (const int*)d_in[1];
  const int* dst = src + E;
  const float* g1_lin_W = (const float*)d_in[2];
  const float* g1_lin_b = (const float*)d_in[3];
  const float* g1_c1_W = (const float*)d_in[4];
  const float* g1_c1_b = (const float*)d_in[5];
  const float* g1_c2_W = (const float*)d_in[6];
  const float* g1_c2_b = (const float*)d_in[7];
  const float* g1_n1_g = (const float*)d_in[8];
  const float* g1_n1_b = (const float*)d_in[9];
  const float* g1_n2_g = (const float*)d_in[10];
  const float* g1_n2_b = (const float*)d_in[11];
  const float* g2_lin_W = (const float*)d_in[12];
  const float* g2_lin_b = (const float*)d_in[13];
  const float* g2_c1_W = (const float*)d_in[14];
  const float* g2_c1_b = (const float*)d_in[15];
  const float* g2_c2_W = (const float*)d_in[16];
  const float* g2_c2_b = (const float*)d_in[17];
  const float* g2_n1_g = (const float*)d_in[18];
  const float* g2_n1_b = (const float*)d_in[19];
  const float* g2_n2_g = (const float*)d_in[20];
  const float* g2_n2_b = (const float*)d_in[21];
  const float* out_W = (const float*)d_in[22];
  const float* out_b = (const float*)d_in[23];
  const float* n1_g = (const float*)d_in[24];
  const float* n1_b = (const float*)d_in[25];
  const float* l1_W = (const float*)d_in[26];
  const float* l1_b = (const float*)d_in[27];
  const float* n2_g = (const float*)d_in[28];
  const float* n2_b = (const float*)d_in[29];
  const float* l2_W = (const float*)d_in[30];
  const float* l2_b = (const float*)d_in[31];

  float* out = (float*)d_out;

  // ---- workspace carve-up
  size_t off = 0;
  auto alloc = [&](size_t bytes) -> void* {
    void* p = (char*)d_ws + off;
    off += (bytes + 255) & ~(size_t)255;
    return p;
  };
  ushort* B1 = (ushort*)alloc((size_t)N * 256 * 2);  // x_in block1 (bf16 residual src)
  ushort* B2 = (ushort*)alloc((size_t)N * 128 * 2);  // x_in block2 (bf16 residual src)
  ushort* sA = (ushort*)alloc((size_t)N * 256 * 2);  // rotating bf16 slot A
  ushort* sB = (ushort*)alloc((size_t)N * 256 * 2);  // rotating bf16 slot B
  int* cnt = (int*)alloc((size_t)N * 4);
  int* row_ptr = (int*)alloc((size_t)(N + 1) * 4);
  int* cursor = (int*)alloc((size_t)N * 4);
  int* col = (int*)alloc((size_t)E * 4);
  int* part = (int*)alloc(1024 * 4);
  float* dis = (float*)alloc((size_t)N * 4);
  float* sums = (float*)alloc(6 * 512 * 4);

  const int wk[9] = {128, 256, 256, 256, 128, 128, 128, 128, 64};
  const int wo[9] = {256, 256, 256, 128, 128, 128, 128, 64, 64};
  const float* wsrc[9] = {g1_lin_W, g1_c1_W, g1_c2_W, g2_lin_W, g2_c1_W,
                          g2_c2_W, out_W, l1_W, l2_W};
  ushort* whi[9];
  ushort* wlo[9];
  for (int i = 0; i < 9; ++i) {
    whi[i] = (ushort*)alloc((size_t)wk[i] * wo[i] * 2);
    wlo[i] = (ushort*)alloc((size_t)wk[i] * wo[i] * 2);
  }
  (void)ws_size;
  (void)n_in;
  (void)out_size;

  const int NB = IDIV(N, 256);
  const int GT = IDIV(N, 256);  // BM=256 grid x
  const float invN = 1.0f / (float)N;
  float* sums0 = sums + 0 * 512;
  float* sums1 = sums + 1 * 512;
  float* sums2 = sums + 2 * 512;
  float* sums3 = sums + 3 * 512;
  float* sums4 = sums + 4 * 512;
  float* sums5 = sums + 5 * 512;

  // ---- CSR build + weight prep
  k_zero_i32<<<NB, 256, 0, stream>>>(cnt, N);
  k_zero_f32<<<IDIV(6 * 512, 256), 256, 0, stream>>>(sums, 6 * 512);
  {
    WPack p;
    for (int i = 0; i < 9; ++i) p.s[i] = WSpec{wsrc[i], whi[i], wlo[i], wk[i], wo[i]};
    k_wprep<<<dim3(64, 9), 256, 0, stream>>>(p);
  }
  k_count<<<IDIV(E, 256), 256, 0, stream>>>(dst, E, cnt);
  k_scan_partial<<<NB, 256, 0, stream>>>(cnt, N, part);
  k_scan_offsets<<<1, 256, 0, stream>>>(part, NB);
  k_scan_final<<<NB, 256, 0, stream>>>(cnt, N, part, row_ptr);
  k_cursor_dis<<<NB, 256, 0, stream>>>(row_ptr, cnt, cursor, dis, row_ptr + N, N, E);
  k_scatter<<<IDIV(E, 256), 256, 0, stream>>>(src, dst, E, cursor, col);

  // ================= block 1 (in 128, hid 256) =================
  k_gemm5<128, 256, 1, false, true, true, true, true, false><<<dim3(GT, 4), 512, 0, stream>>>(
      x_vert, whi[0], wlo[0], g1_lin_b, nullptr, nullptr, nullptr, 0.f, nullptr, B1, sums0, N);
  k_gemm5<256, 256, 2, false, false, false, true, false, true><<<dim3(GT, 4), 512, 0, stream>>>(
      B1, whi[1], wlo[1], nullptr, sums0, g1_n1_g, g1_n1_b, invN, dis, sB, nullptr, N);
  k_agg5<256, false><<<IDIV(N, 4), 256, 0, stream>>>(
      sB, row_ptr, col, dis, g1_c1_b, nullptr, nullptr, nullptr, nullptr, 0.f, sA, N);
  k_colstats_bf<256><<<NB, 256, 0, stream>>>(sA, N, sums1);
  k_gemm5<256, 256, 2, false, false, false, true, false, true><<<dim3(GT, 4), 512, 0, stream>>>(
      sA, whi[2], wlo[2], nullptr, sums1, g1_n2_g, g1_n2_b, invN, dis, sB, nullptr, N);
  k_agg5<256, true><<<IDIV(N, 4), 256, 0, stream>>>(
      sB, row_ptr, col, dis, g1_c2_b, B1, sums0, g1_n1_g, g1_n1_b, invN, sA, N);

  // ================= block 2 (in 256, hid 128) =================
  k_gemm5<256, 128, 0, false, true, true, true, true, false><<<dim3(GT, 2), 512, 0, stream>>>(
      sA, whi[3], wlo[3], g2_lin_b, nullptr, nullptr, nullptr, 0.f, nullptr, B2, sums2, N);
  k_gemm5<128, 128, 2, false, false, false, true, false, true><<<dim3(GT, 2), 512, 0, stream>>>(
      B2, whi[4], wlo[4], nullptr, sums2, g2_n1_g, g2_n1_b, invN, dis, sB, nullptr, N);
  k_agg5<128, false><<<IDIV(N, 4), 256, 0, stream>>>(
      sB, row_ptr, col, dis, g2_c1_b, nullptr, nullptr, nullptr, nullptr, 0.f, sA, N);
  k_colstats_bf<128><<<NB, 256, 0, stream>>>(sA, N, sums3);
  k_gemm5<128, 128, 2, false, false, false, true, false, true><<<dim3(GT, 2), 512, 0, stream>>>(
      sA, whi[5], wlo[5], nullptr, sums3, g2_n2_g, g2_n2_b, invN, dis, sB, nullptr, N);
  k_agg5<128, true><<<IDIV(N, 4), 256, 0, stream>>>(
      sB, row_ptr, col, dis, g2_c2_b, B2, sums2, g2_n1_g, g2_n1_b, invN, sA, N);

  // ================= head =================
  k_gemm5<128, 128, 0, false, true, true, true, true, false><<<dim3(GT, 2), 512, 0, stream>>>(
      sA, whi[6], wlo[6], out_b, nullptr, nullptr, nullptr, 0.f, nullptr, sB, sums4, N);
  k_gemm5<128, 64, 2, true, true, true, true, true, false><<<dim3(GT, 1), 512, 0, stream>>>(
      sB, whi[7], wlo[7], l1_b, sums4, n1_g, n1_b, invN, nullptr, sA, sums5, N);
  k_gemm5<64, 64, 2, true, true, false, false, true, false><<<dim3(GT, 1), 512, 0, stream>>>(
      sA, whi[8], wlo[8], l2_b, sums5, n2_g, n2_b, invN, nullptr, out, nullptr, N);
}